// Round 7
// baseline (647.601 us; speedup 1.0000x reference)
//
#include <hip/hip_runtime.h>
#include <math.h>

#define N_IMG 16
#define CIN   64
#define CMID  128
#define CO    32
#define KHD   16
#define HL    128
#define WL    128
#define HO    256
#define WO    256
#define EPSV  1e-5f

typedef float f32x4 __attribute__((ext_vector_type(4)));
typedef _Float16 h8v __attribute__((ext_vector_type(8)));
typedef _Float16 h2v __attribute__((ext_vector_type(2)));

// ---------------- workspace layout (floats) ----------------
// [0, 33554432)            t (16,128,128,128)       -- dead after K3
// [33554432, 50331648)     refodd (16,16,256,256)   -- K5 overwrites in place with gx
// [50331648, +8192)        S1p (4,2048)
// [+8192, +8192)           S2p (4,2048)
// [+..., 65536 f32 slot)   wAf: f16 A-fragments (16 n x 4 cb x 2 mt x 64 lane x 8)
// [+..., 512)              beff (16,32)
// [+..., 8192)             w1T (64,128)  [c][o]
// gy lives in d_out (K6 stages its gy tile into LDS before overwriting).

// K0: transpose conv1 weights to [c][o] so K1 can read them wave-uniformly.
__global__ __launch_bounds__(256) void k0_transpose(const float* __restrict__ w1,
                                                    float* __restrict__ w1T) {
  int tid = threadIdx.x;
  for (int f = tid; f < CMID * CIN; f += 256) {
    int o = f >> 6, c = f & 63;
    w1T[c * CMID + o] = w1[f];
  }
}

// K1: t[n][o][y][x] = conv1_b[o] + sum_c conv1_w[o][c] * lo[n][c][y][x]
__global__ __launch_bounds__(512) void k1_conv1(const float* __restrict__ lo,
                                                const float* __restrict__ w1T,
                                                const float* __restrict__ b1,
                                                float* __restrict__ t) {
  int blk = blockIdx.x;        // n*128 + y
  int n = blk >> 7, y = blk & 127;
  __shared__ float lo_l[CIN * WL];    // [c][x]  32 KB
  int tid = threadIdx.x;
  const float* lo_base = lo + (size_t)n * CIN * (HL * WL) + y * WL;
  for (int f = tid; f < CIN * WL / 4; f += 512) {
    int c = f >> 5, xi = f & 31;
    ((float4*)lo_l)[f] = *(const float4*)(lo_base + (size_t)c * (HL * WL) + xi * 4);
  }
  __syncthreads();

  int wave = __builtin_amdgcn_readfirstlane(tid >> 6);  // force wave-uniform
  int lane = tid & 63;
  int half = wave >> 2;   // x-half
  int og   = wave & 3;    // 32-output group
  int x = half * 64 + lane;

  float acc[32];
#pragma unroll
  for (int o = 0; o < 32; ++o) acc[o] = 0.f;

  const float* wbase = w1T + og * 32;   // [c][o], stride CMID; uniform
  for (int c = 0; c < CIN; ++c) {
    float lv = lo_l[c * WL + x];
    const float* wr = wbase + c * CMID;
#pragma unroll
    for (int o = 0; o < 32; ++o) acc[o] += wr[o] * lv;
  }
  const float* bb = b1 + og * 32;       // uniform
  float* tb = t + ((size_t)n * CMID + og * 32) * (HL * WL) + y * WL + x;
#pragma unroll
  for (int o = 0; o < 32; ++o) tb[(size_t)o * (HL * WL)] = acc[o] + bb[o];
}

// Fast erf (A&S 7.1.26, |err| <= 1.5e-7), DIV-FREE: v_rcp instead of IEEE divide.
__device__ __forceinline__ float erf_fast(float x) {
  float ax = fabsf(x);
  float t = __builtin_amdgcn_rcpf(fmaf(0.3275911f, ax, 1.f));
  float e = __expf(-ax * ax);
  float poly = t * (0.254829592f +
              t * (-0.284496736f +
              t * (1.421413741f +
              t * (-1.453152027f +
              t * 1.061405429f))));
  float r = fmaf(-poly, e, 1.f);
  return copysignf(r, x);
}

__device__ __forceinline__ float gelu_fast(float v) {
  float h = 0.5f * v;
  return fmaf(h, erf_fast(v * 0.70710678118654752f), h);
}

// K2: per (q, n, c): partial sum & sumsq of GELU(bilinear_upsample(t[n,c]))
__global__ __launch_bounds__(256) void k2_stats(const float* __restrict__ t,
                                                float* __restrict__ S1p,
                                                float* __restrict__ S2p) {
  int blk = blockIdx.x;          // q*2048 + nc
  int nc = blk & 2047, q = blk >> 11;
  __shared__ float img[34 * WL]; // 17 KB
  __shared__ float red[16];
  int tid = threadIdx.x;
  int i0 = q * 64;
  int ylo = (int)floorf(i0 * (127.f / 255.f));
  int yhi = min((int)floorf((i0 + 63) * (127.f / 255.f)) + 1, 127);
  int nr = yhi - ylo + 1;
  const float* tb = t + (size_t)nc * (HL * WL) + ylo * WL;
  for (int f = tid; f < nr * (WL / 4); f += 256)
    ((float4*)img)[f] = ((const float4*)tb)[f];
  __syncthreads();

  float xs = tid * (127.f / 255.f);
  float x0f = floorf(xs);
  int x0 = (int)x0f, x1 = min(x0 + 1, 127);
  float wx = xs - x0f, omwx = 1.f - wx;
  float sum = 0.f, ssq = 0.f;
  for (int k = 0; k < 64; ++k) {
    float ys = (i0 + k) * (127.f / 255.f);
    float y0f = floorf(ys);
    int y0 = (int)y0f - ylo, y1 = min((int)y0f + 1, 127) - ylo;
    float wy = ys - y0f, omwy = 1.f - wy;
    float r0 = img[y0 * WL + x0] * omwx + img[y0 * WL + x1] * wx;
    float r1 = img[y1 * WL + x0] * omwx + img[y1 * WL + x1] * wx;
    float g = gelu_fast(r0 * omwy + r1 * wy);
    sum += g; ssq += g * g;
  }
  int lane = tid & 63, w = tid >> 6;
#pragma unroll
  for (int d = 32; d; d >>= 1) {
    sum += __shfl_xor(sum, d, 64);
    ssq += __shfl_xor(ssq, d, 64);
  }
  if (lane == 0) { red[w] = sum; red[8 + w] = ssq; }
  __syncthreads();
  if (tid == 0) {
    S1p[blk] = red[0] + red[1] + red[2] + red[3];
    S2p[blk] = red[8] + red[9] + red[10] + red[11];
  }
}

// K2b: fold GN + SE + conv2 into per-image effective weights + bias.
// Weights are emitted as f16 MFMA A-fragments for v_mfma_f32_16x16x32_f16:
//   A[row=o&15][k=c&31] of tile (cb=c>>5, mt=o>>4); lane = ((c&31)>>3)*16 + (o&15),
//   element j = c&7  ->  wAf[((n*4+cb)*2+mt)*512 + lane*8 + j]
__global__ __launch_bounds__(128) void k2b_prep(const float* __restrict__ S1p,
                                                const float* __restrict__ S2p,
                                                const float* __restrict__ gn_w,
                                                const float* __restrict__ gn_b,
                                                const float* __restrict__ se_w1,
                                                const float* __restrict__ se_w2,
                                                const float* __restrict__ w2,
                                                unsigned short* __restrict__ wAf,
                                                float* __restrict__ beff) {
  int n = blockIdx.x, c = threadIdx.x;
  int nc = n * 128 + c;
  __shared__ float mArr[128], eArr[128], pArr[128], hArr[16], dArr[128];
  const float inv = 1.f / 65536.f;
  float m  = (S1p[nc] + S1p[2048 + nc] + S1p[4096 + nc] + S1p[6144 + nc]) * inv;
  float e2 = (S2p[nc] + S2p[2048 + nc] + S2p[4096 + nc] + S2p[6144 + nc]) * inv;
  mArr[c] = m; eArr[c] = e2;
  __syncthreads();
  int g0 = (c >> 6) << 6;
  float mu = 0.f, E2 = 0.f;
  for (int q = 0; q < 64; ++q) { mu += mArr[g0 + q]; E2 += eArr[g0 + q]; }
  mu *= (1.f / 64.f); E2 *= (1.f / 64.f);
  float var = E2 - mu * mu;
  float rs = rsqrtf(var + EPSV);
  float gw = gn_w[c], gb = gn_b[c];
  pArr[c] = (m - mu) * rs * gw + gb;
  __syncthreads();
  if (c < 16) {
    float h = 0.f;
    for (int q = 0; q < 128; ++q) h += se_w1[c * 128 + q] * pArr[q];
    hArr[c] = fmaxf(h, 0.f);
  }
  __syncthreads();
  float sacc = 0.f;
  for (int q = 0; q < 16; ++q) sacc += se_w2[c * 16 + q] * hArr[q];
  float s = __builtin_amdgcn_rcpf(1.f + __expf(-sacc));
  float a = s * gw * rs;
  float d = s * (gb - gw * rs * mu);
  dArr[c] = d;
  __syncthreads();
  int cb = c >> 5;
  int lbase = ((c >> 3) & 3) << 4;   // (lane>>4) = (c&31)>>3
  int j = c & 7;
#pragma unroll
  for (int o = 0; o < 32; ++o) {
    int mt = o >> 4;
    size_t idx = ((size_t)n * 8 + (size_t)(cb * 2 + mt)) * 512 +
                 (size_t)((lbase + (o & 15)) * 8 + j);
    _Float16 hv = (_Float16)(w2[o * 128 + c] * a);
    wAf[idx] = __builtin_bit_cast(unsigned short, hv);
  }
  if (c < 32) {
    float bb = 0.f;
    for (int q = 0; q < 128; ++q) bb += w2[c * 128 + q] * dArr[q];
    beff[n * 32 + c] = bb;
  }
}

// K3: MFMA conv2 + row softmax/cumsum epilogue.
// LDS squeezed to exactly 32 KB (5 blocks/CU, was 37.4 KB / 4 blocks):
//  - ch[4096] (no pad; glb at byte 16384; the guard write zeroes glb[0..15] so
//    the wx==0 read at tid 255 is NaN-safe: f16 bit patterns can't alias f32
//    NaN/Inf, and the operand is multiplied by exactly 0)
//  - D-phase scratch: stride 128B + XOR-8 chunk swizzle (conflict-minimal both
//    directions; the old 144B stride was 4-way conflicted on writes)
//  - lmaxS/lsumS alias smem[0..127] behind an extra barrier
__global__ __launch_bounds__(256, 5) void k3_ref(const float* __restrict__ t,
                                                 const unsigned short* __restrict__ wAf,
                                                 const float* __restrict__ beff,
                                                 float* __restrict__ refodd,
                                                 float* __restrict__ gy) {
  int blk = blockIdx.x;  // n*256 + i
  int n = blk >> 8, i = blk & 255;
  __shared__ float smem[8192];        // 32 KB exactly
  int tid = threadIdx.x;
  float* ch = smem;                   // [0, 4096) floats (phase AB)
  char* glb = (char*)(smem + 4096);   // byte 16384, 16 KB f16 B-panel (phase AB)
  float* lmaxS = smem;                // epilogue alias (behind barrier)
  float* lsumS = smem + 64;
  const float* bn = beff + n * CO;    // uniform

  if (tid < 4) ch[4096 + tid] = 0.f;  // guard: finite bits for the x0+1 read at cc=31

  int lane = tid & 63;
  h8v wfrag[8];                       // A-frags: [cb][mt], resident all kernel
#pragma unroll
  for (int u = 0; u < 8; ++u)
    wfrag[u] = *(const h8v*)(wAf + ((size_t)n * 8 + u) * 512 + lane * 8);

  float ys = i * (127.f / 255.f);
  float y0f = floorf(ys);
  int y0 = (int)y0f, y1 = min(y0 + 1, 127);
  float wy = ys - y0f, omwy = 1.f - wy;
  float xs = tid * (127.f / 255.f);
  float x0f = floorf(xs);
  int x0 = (int)x0f;
  float wx = xs - x0f, omwx = 1.f - wx;

  f32x4 acc[2][4];
#pragma unroll
  for (int mt = 0; mt < 2; ++mt)
#pragma unroll
    for (int xt = 0; xt < 4; ++xt)
      acc[mt][xt] = (f32x4){0.f, 0.f, 0.f, 0.f};

  int wv6 = tid & 192;                // wave base pixel
  int cg = (tid >> 4) & 3;            // lane's k-granule within the B-frag
  const size_t tbase = (size_t)n * CMID * (HL * WL);

#pragma unroll
  for (int cb = 0; cb < 4; ++cb) {
    __syncthreads();                  // prev g-compute reads of ch done
    for (int f = tid; f < 32 * 32; f += 256) {
      int cc = f >> 5, x4 = (f & 31) * 4;
      const float* base = t + tbase + (size_t)(cb * 32 + cc) * (HL * WL) + x4;
      float4 a = *(const float4*)(base + y0 * WL);
      float4 b = *(const float4*)(base + y1 * WL);
      float4 cmb;
      cmb.x = fmaf(a.x, omwy, b.x * wy);
      cmb.y = fmaf(a.y, omwy, b.y * wy);
      cmb.z = fmaf(a.z, omwy, b.z * wy);
      cmb.w = fmaf(a.w, omwy, b.w * wy);
      *(float4*)&ch[cc * 128 + x4] = cmb;
    }
    __syncthreads();                  // ch ready

    unsigned gp[16];
#pragma unroll
    for (int p = 0; p < 16; ++p) {
      const float* c0 = &ch[(2 * p) * 128 + x0];
      float g0 = gelu_fast(fmaf(c0[0], omwx, c0[1] * wx));
      const float* c1 = c0 + 128;
      float g1 = gelu_fast(fmaf(c1[0], omwx, c1[1] * wx));
      h2v hv;
      hv.x = (_Float16)g0;            // RNE casts for accuracy
      hv.y = (_Float16)g1;
      gp[p] = __builtin_bit_cast(unsigned, hv);
    }
    // write this pixel's 64B B-row, 16B chunks XOR-swizzled to spread banks
    int xsw = (tid & 3) ^ ((tid >> 2) & 3);
    char* grow = glb + tid * 64;
    uint4 q;
    q.x = gp[0];  q.y = gp[1];  q.z = gp[2];  q.w = gp[3];
    *(uint4*)(grow + ((0 ^ xsw) << 4)) = q;
    q.x = gp[4];  q.y = gp[5];  q.z = gp[6];  q.w = gp[7];
    *(uint4*)(grow + ((1 ^ xsw) << 4)) = q;
    q.x = gp[8];  q.y = gp[9];  q.z = gp[10]; q.w = gp[11];
    *(uint4*)(grow + ((2 ^ xsw) << 4)) = q;
    q.x = gp[12]; q.y = gp[13]; q.z = gp[14]; q.w = gp[15];
    *(uint4*)(grow + ((3 ^ xsw) << 4)) = q;
    __syncthreads();                  // gl ready

#pragma unroll
    for (int xt = 0; xt < 4; ++xt) {
      int xrow = wv6 + xt * 16 + (tid & 15);
      int slot = cg ^ (xrow & 3) ^ ((xrow >> 2) & 3);
      h8v bfrag = *(const h8v*)(glb + xrow * 64 + (slot << 4));
      acc[0][xt] = __builtin_amdgcn_mfma_f32_16x16x32_f16(wfrag[cb * 2 + 0], bfrag,
                                                          acc[0][xt], 0, 0, 0);
      acc[1][xt] = __builtin_amdgcn_mfma_f32_16x16x32_f16(wfrag[cb * 2 + 1], bfrag,
                                                          acc[1][xt], 0, 0, 0);
    }
  }

  __syncthreads();                    // all MFMA B-reads done before smem reuse
  // D-frags -> LDS [x][o]: stride 128B, XOR-8 swizzle (conflict-minimal)
#pragma unroll
  for (int mt = 0; mt < 2; ++mt)
#pragma unroll
    for (int xt = 0; xt < 4; ++xt) {
      int xrow = wv6 + xt * 16 + (tid & 15);
      int go = mt * 4 + ((tid >> 4) & 3);   // o-chunk index (4 f32)
      *(f32x4*)((char*)smem + xrow * 128 + ((go ^ (xrow & 7)) << 4)) = acc[mt][xt];
    }
  __syncthreads();

  float accv[32];
#pragma unroll
  for (int gg = 0; gg < 8; ++gg) {
    f32x4 v = *(const f32x4*)((char*)smem + tid * 128 + ((gg ^ (tid & 7)) << 4));
    accv[4 * gg + 0] = v[0];
    accv[4 * gg + 1] = v[1];
    accv[4 * gg + 2] = v[2];
    accv[4 * gg + 3] = v[3];
  }
#pragma unroll
  for (int o = 0; o < 32; ++o) accv[o] += bn[o];

  __syncthreads();                    // accv reads done; lmaxS/lsumS may alias smem

  // odd channels -> refodd
#pragma unroll
  for (int k = 0; k < 16; ++k)
    refodd[(((size_t)(n * 16 + k)) * HO + i) * WO + tid] = accv[2 * k + 1];

  // even channels: row softmax + cumsum -> gy (batched phases).
  int lane2 = tid & 63, w = tid >> 6;
#pragma unroll
  for (int k = 0; k < 16; ++k) {
    float m = accv[2 * k];
#pragma unroll
    for (int d = 32; d; d >>= 1) m = fmaxf(m, __shfl_xor(m, d, 64));
    if (lane2 == 0) lmaxS[k * 4 + w] = m;
  }
  __syncthreads();
  float pk[16];
#pragma unroll
  for (int k = 0; k < 16; ++k) {
    float m = fmaxf(fmaxf(lmaxS[k * 4 + 0], lmaxS[k * 4 + 1]),
                    fmaxf(lmaxS[k * 4 + 2], lmaxS[k * 4 + 3]));
    float p = __expf(accv[2 * k] - m);
#pragma unroll
    for (int d = 1; d < 64; d <<= 1) {
      float q = __shfl_up(p, d, 64);
      if (lane2 >= d) p += q;
    }
    pk[k] = p;
    if (lane2 == 63) lsumS[k * 4 + w] = p;
  }
  __syncthreads();
#pragma unroll
  for (int k = 0; k < 16; ++k) {
    float off = 0.f, tot = 0.f;
#pragma unroll
    for (int q = 0; q < 4; ++q) {
      float x = lsumS[k * 4 + q];
      tot += x;
      if (q < w) off += x;
    }
    gy[((size_t)(n * 16 + k) * HO + i) * WO + tid] =
        (pk[k] + off) * (255.f * __builtin_amdgcn_rcpf(tot));
  }
}

// K5: column softmax+cumsum -> gx, in place over refodd.
__global__ __launch_bounds__(256) void k5_colscan(float* __restrict__ refodd) {
  int blk = blockIdx.x;           // nk*4 + cg
  int nk = blk >> 2, cg = blk & 3;
  int tid = threadIdx.x;
  int c = tid >> 6, j = tid & 63;
  __shared__ float lmax[4 * 64], lsum[4 * 64];
  float* img = refodd + (size_t)nk * (HO * WO) + cg * 64 + j;

  float p[64];
  float m = -1e30f;
#pragma unroll
  for (int q = 0; q < 64; ++q) {
    p[q] = img[(size_t)(c * 64 + q) * WO];
    m = fmaxf(m, p[q]);
  }
  lmax[c * 64 + j] = m;
  __syncthreads();
  m = fmaxf(fmaxf(lmax[j], lmax[64 + j]), fmaxf(lmax[128 + j], lmax[192 + j]));
  float s = 0.f;
#pragma unroll
  for (int q = 0; q < 64; ++q) {
    p[q] = __expf(p[q] - m);
    s += p[q];
  }
  lsum[c * 64 + j] = s;
  __syncthreads();
  float off = 0.f, tot = 0.f;
#pragma unroll
  for (int q2 = 0; q2 < 4; ++q2) {
    float x = lsum[q2 * 64 + j];
    tot += x;
    if (q2 < c) off += x;
  }
  float inv255 = 255.f * __builtin_amdgcn_rcpf(tot);
  float run = off;
#pragma unroll
  for (int q = 0; q < 64; ++q) {
    run += p[q];
    img[(size_t)(c * 64 + q) * WO] = run * inv255;
  }
}

// K6 v4: coordinates staged COALESCED into LDS, transposed per-thread LDS read,
// all 64 hi taps issued + pinned by compiler memory barrier, bilinear, dense
// stores through the gxl tile. (unchanged from round 6)
__global__ __launch_bounds__(256, 4) void k6_sample_t4(const float* __restrict__ gx,
                                                       const float* __restrict__ hi,
                                                       float* out) {
  int blk = blockIdx.x;            // nk*16 + ti*4 + tj
  int nk = blk >> 4, ti = (blk >> 2) & 3, tj = blk & 3;
  __shared__ float gxl[64 * 65];   // coords; becomes result tile
  __shared__ float gyl[64 * 65];
  int tid = threadIdx.x;
  const size_t ibase = (size_t)nk * (HO * WO);
  const size_t tb = ibase + (size_t)(ti * 64) * WO + tj * 64;
  const float* himg = hi + ibase;

  // Phase 0: dense coalesced stage of gx and gy (gy aliases out).
#pragma unroll
  for (int ph = 0; ph < 4; ++ph) {
    int r = ph * 16 + (tid >> 4), c4 = (tid & 15) * 4;
    float4 vx = *(const float4*)(gx + tb + (size_t)r * WO + c4);
    float4 vy = *(const float4*)(out + tb + (size_t)r * WO + c4);
    int a = r * 65 + c4;
    gxl[a] = vx.x; gxl[a + 1] = vx.y; gxl[a + 2] = vx.z; gxl[a + 3] = vx.w;
    gyl[a] = vy.x; gyl[a + 1] = vy.y; gyl[a + 2] = vy.z; gyl[a + 3] = vy.w;
  }
  __syncthreads();

  // Phase 1: thread (row il, cols jg*16..+15) reads its 32 coords from LDS
  // (lane-stride 65 -> 2-way bank alias, free) and issues ALL 64 taps.
  int il = tid & 63, jg = tid >> 6;
  const float* lgx = &gxl[il * 65 + jg * 16];
  const float* lgy = &gyl[il * 65 + jg * 16];
  float wxa[16], wya[16];
  float v00[16], v01[16], v10[16], v11[16];
#pragma unroll
  for (int s = 0; s < 16; ++s) {
    float xf = lgx[s], yf = lgy[s];
    float x0f = floorf(xf), y0f = floorf(yf);
    wxa[s] = xf - x0f; wya[s] = yf - y0f;
    int x0 = (int)x0f, y0 = (int)y0f;
    int x1 = min(x0 + 1, 255), y1 = min(y0 + 1, 255);
    const float* r0 = himg + y0 * WO;
    const float* r1 = himg + y1 * WO;
    v00[s] = r0[x0]; v01[s] = r0[x1];
    v10[s] = r1[x0]; v11[s] = r1[x1];
  }
  // Real compiler memory barrier: loads cannot sink past it.
  asm volatile("" ::: "memory");
  __syncthreads();

  // Phase 2: bilinear combine; results overwrite gxl.
  float* lrow = &gxl[il * 65 + jg * 16];
#pragma unroll
  for (int s = 0; s < 16; ++s) {
    float top = fmaf(v01[s] - v00[s], wxa[s], v00[s]);
    float bot = fmaf(v11[s] - v10[s], wxa[s], v10[s]);
    lrow[s] = fmaf(bot - top, wya[s], top);
  }
  __syncthreads();

  // Phase 3: dense store (wave covers 16 full 256B rows).
#pragma unroll
  for (int ph = 0; ph < 4; ++ph) {
    int r = ph * 16 + (tid >> 4), c4 = (tid & 15) * 4;
    int a = r * 65 + c4;
    float4 v;
    v.x = gxl[a]; v.y = gxl[a + 1]; v.z = gxl[a + 2]; v.w = gxl[a + 3];
    *(float4*)(out + tb + (size_t)r * WO + c4) = v;
  }
}

extern "C" void kernel_launch(void* const* d_in, const int* in_sizes, int n_in,
                              void* d_out, int out_size, void* d_ws, size_t ws_size,
                              hipStream_t stream) {
  (void)in_sizes; (void)n_in; (void)out_size; (void)ws_size;
  const float* lo  = (const float*)d_in[0];
  const float* hi  = (const float*)d_in[1];
  const float* w1  = (const float*)d_in[2];
  const float* b1  = (const float*)d_in[3];
  const float* gnw = (const float*)d_in[4];
  const float* gnb = (const float*)d_in[5];
  const float* sw1 = (const float*)d_in[6];
  const float* sw2 = (const float*)d_in[7];
  const float* w2  = (const float*)d_in[8];
  float* ws = (float*)d_ws;
  float* t       = ws;                    // 33,554,432 floats
  float* refodd  = ws + 33554432;         // 16,777,216 floats (becomes gx in place)
  float* S1p     = ws + 50331648;         // 8192
  float* S2p     = S1p + 8192;            // 8192
  unsigned short* wAf = (unsigned short*)(S2p + 8192);  // 65,536 f16 in old w2effT slot
  float* beff    = S2p + 8192 + 65536;    // 512
  float* w1T     = beff + 512;            // 8192
  float* out     = (float*)d_out;
  float* gybuf   = out;                   // gy aliases d_out

  k0_transpose<<<dim3(1), dim3(256), 0, stream>>>(w1, w1T);
  k1_conv1<<<dim3(2048), dim3(512), 0, stream>>>(lo, w1T, b1, t);
  k2_stats<<<dim3(8192), dim3(256), 0, stream>>>(t, S1p, S2p);
  k2b_prep<<<dim3(16), dim3(128), 0, stream>>>(S1p, S2p, gnw, gnb, sw1, sw2, w2, wAf, beff);
  k3_ref<<<dim3(4096), dim3(256), 0, stream>>>(t, wAf, beff, refodd, gybuf);
  k5_colscan<<<dim3(1024), dim3(256), 0, stream>>>(refodd);
  k6_sample_t4<<<dim3(4096), dim3(256), 0, stream>>>(refodd, hi, out);
}

// Round 8
// 628.254 us; speedup vs baseline: 1.0308x; 1.0308x over previous
//
#include <hip/hip_runtime.h>
#include <math.h>

#define N_IMG 16
#define CIN   64
#define CMID  128
#define CO    32
#define KHD   16
#define HL    128
#define WL    128
#define HO    256
#define WO    256
#define EPSV  1e-5f

typedef float f32x4 __attribute__((ext_vector_type(4)));
typedef _Float16 h8v __attribute__((ext_vector_type(8)));
typedef _Float16 h2v __attribute__((ext_vector_type(2)));

// ---------------- workspace layout (floats) ----------------
// [0, 33554432)            t (16,128,128,128)       -- dead after K3
// [33554432, 50331648)     refodd (16,16,256,256)   -- K5 overwrites in place with gx
// [50331648, +8192)        S1p (4,2048)
// [+8192, +8192)           S2p (4,2048)
// [+..., 65536 f32 slot)   wAf: f16 A-fragments (16 n x 4 cb x 2 mt x 64 lane x 8)
// [+..., 512)              beff (16,32)
// [+..., 8192)             w1T (64,128)  [c][o]
// gy lives in d_out (K6 stages its gy tile into LDS before overwriting).

// K0: transpose conv1 weights to [c][o] so K1 can read them wave-uniformly.
__global__ __launch_bounds__(256) void k0_transpose(const float* __restrict__ w1,
                                                    float* __restrict__ w1T) {
  int tid = threadIdx.x;
  for (int f = tid; f < CMID * CIN; f += 256) {
    int o = f >> 6, c = f & 63;
    w1T[c * CMID + o] = w1[f];
  }
}

// K1: t[n][o][y][x] = conv1_b[o] + sum_c conv1_w[o][c] * lo[n][c][y][x]
__global__ __launch_bounds__(512) void k1_conv1(const float* __restrict__ lo,
                                                const float* __restrict__ w1T,
                                                const float* __restrict__ b1,
                                                float* __restrict__ t) {
  int blk = blockIdx.x;        // n*128 + y
  int n = blk >> 7, y = blk & 127;
  __shared__ float lo_l[CIN * WL];    // [c][x]  32 KB
  int tid = threadIdx.x;
  const float* lo_base = lo + (size_t)n * CIN * (HL * WL) + y * WL;
  for (int f = tid; f < CIN * WL / 4; f += 512) {
    int c = f >> 5, xi = f & 31;
    ((float4*)lo_l)[f] = *(const float4*)(lo_base + (size_t)c * (HL * WL) + xi * 4);
  }
  __syncthreads();

  int wave = __builtin_amdgcn_readfirstlane(tid >> 6);  // force wave-uniform
  int lane = tid & 63;
  int half = wave >> 2;   // x-half
  int og   = wave & 3;    // 32-output group
  int x = half * 64 + lane;

  float acc[32];
#pragma unroll
  for (int o = 0; o < 32; ++o) acc[o] = 0.f;

  const float* wbase = w1T + og * 32;   // [c][o], stride CMID; uniform
  for (int c = 0; c < CIN; ++c) {
    float lv = lo_l[c * WL + x];
    const float* wr = wbase + c * CMID;
#pragma unroll
    for (int o = 0; o < 32; ++o) acc[o] += wr[o] * lv;
  }
  const float* bb = b1 + og * 32;       // uniform
  float* tb = t + ((size_t)n * CMID + og * 32) * (HL * WL) + y * WL + x;
#pragma unroll
  for (int o = 0; o < 32; ++o) tb[(size_t)o * (HL * WL)] = acc[o] + bb[o];
}

// Fast erf (A&S 7.1.26, |err| <= 1.5e-7), DIV-FREE: v_rcp instead of IEEE divide.
__device__ __forceinline__ float erf_fast(float x) {
  float ax = fabsf(x);
  float t = __builtin_amdgcn_rcpf(fmaf(0.3275911f, ax, 1.f));
  float e = __expf(-ax * ax);
  float poly = t * (0.254829592f +
              t * (-0.284496736f +
              t * (1.421413741f +
              t * (-1.453152027f +
              t * 1.061405429f))));
  float r = fmaf(-poly, e, 1.f);
  return copysignf(r, x);
}

__device__ __forceinline__ float gelu_fast(float v) {
  float h = 0.5f * v;
  return fmaf(h, erf_fast(v * 0.70710678118654752f), h);
}

// K2: per (q, n, c): partial sum & sumsq of GELU(bilinear_upsample(t[n,c]))
__global__ __launch_bounds__(256) void k2_stats(const float* __restrict__ t,
                                                float* __restrict__ S1p,
                                                float* __restrict__ S2p) {
  int blk = blockIdx.x;          // q*2048 + nc
  int nc = blk & 2047, q = blk >> 11;
  __shared__ float img[34 * WL]; // 17 KB
  __shared__ float red[16];
  int tid = threadIdx.x;
  int i0 = q * 64;
  int ylo = (int)floorf(i0 * (127.f / 255.f));
  int yhi = min((int)floorf((i0 + 63) * (127.f / 255.f)) + 1, 127);
  int nr = yhi - ylo + 1;
  const float* tb = t + (size_t)nc * (HL * WL) + ylo * WL;
  for (int f = tid; f < nr * (WL / 4); f += 256)
    ((float4*)img)[f] = ((const float4*)tb)[f];
  __syncthreads();

  float xs = tid * (127.f / 255.f);
  float x0f = floorf(xs);
  int x0 = (int)x0f, x1 = min(x0 + 1, 127);
  float wx = xs - x0f, omwx = 1.f - wx;
  float sum = 0.f, ssq = 0.f;
  for (int k = 0; k < 64; ++k) {
    float ys = (i0 + k) * (127.f / 255.f);
    float y0f = floorf(ys);
    int y0 = (int)y0f - ylo, y1 = min((int)y0f + 1, 127) - ylo;
    float wy = ys - y0f, omwy = 1.f - wy;
    float r0 = img[y0 * WL + x0] * omwx + img[y0 * WL + x1] * wx;
    float r1 = img[y1 * WL + x0] * omwx + img[y1 * WL + x1] * wx;
    float g = gelu_fast(r0 * omwy + r1 * wy);
    sum += g; ssq += g * g;
  }
  int lane = tid & 63, w = tid >> 6;
#pragma unroll
  for (int d = 32; d; d >>= 1) {
    sum += __shfl_xor(sum, d, 64);
    ssq += __shfl_xor(ssq, d, 64);
  }
  if (lane == 0) { red[w] = sum; red[8 + w] = ssq; }
  __syncthreads();
  if (tid == 0) {
    S1p[blk] = red[0] + red[1] + red[2] + red[3];
    S2p[blk] = red[8] + red[9] + red[10] + red[11];
  }
}

// K2b: fold GN + SE + conv2 into per-image effective weights + bias.
// Weights are emitted as f16 MFMA A-fragments for v_mfma_f32_16x16x32_f16:
//   A[row=o&15][k=c&31] of tile (cb=c>>5, mt=o>>4); lane = ((c&31)>>3)*16 + (o&15),
//   element j = c&7  ->  wAf[((n*4+cb)*2+mt)*512 + lane*8 + j]
__global__ __launch_bounds__(128) void k2b_prep(const float* __restrict__ S1p,
                                                const float* __restrict__ S2p,
                                                const float* __restrict__ gn_w,
                                                const float* __restrict__ gn_b,
                                                const float* __restrict__ se_w1,
                                                const float* __restrict__ se_w2,
                                                const float* __restrict__ w2,
                                                unsigned short* __restrict__ wAf,
                                                float* __restrict__ beff) {
  int n = blockIdx.x, c = threadIdx.x;
  int nc = n * 128 + c;
  __shared__ float mArr[128], eArr[128], pArr[128], hArr[16], dArr[128];
  const float inv = 1.f / 65536.f;
  float m  = (S1p[nc] + S1p[2048 + nc] + S1p[4096 + nc] + S1p[6144 + nc]) * inv;
  float e2 = (S2p[nc] + S2p[2048 + nc] + S2p[4096 + nc] + S2p[6144 + nc]) * inv;
  mArr[c] = m; eArr[c] = e2;
  __syncthreads();
  int g0 = (c >> 6) << 6;
  float mu = 0.f, E2 = 0.f;
  for (int q = 0; q < 64; ++q) { mu += mArr[g0 + q]; E2 += eArr[g0 + q]; }
  mu *= (1.f / 64.f); E2 *= (1.f / 64.f);
  float var = E2 - mu * mu;
  float rs = rsqrtf(var + EPSV);
  float gw = gn_w[c], gb = gn_b[c];
  pArr[c] = (m - mu) * rs * gw + gb;
  __syncthreads();
  if (c < 16) {
    float h = 0.f;
    for (int q = 0; q < 128; ++q) h += se_w1[c * 128 + q] * pArr[q];
    hArr[c] = fmaxf(h, 0.f);
  }
  __syncthreads();
  float sacc = 0.f;
  for (int q = 0; q < 16; ++q) sacc += se_w2[c * 16 + q] * hArr[q];
  float s = __builtin_amdgcn_rcpf(1.f + __expf(-sacc));
  float a = s * gw * rs;
  float d = s * (gb - gw * rs * mu);
  dArr[c] = d;
  __syncthreads();
  int cb = c >> 5;
  int lbase = ((c >> 3) & 3) << 4;   // (lane>>4) = (c&31)>>3
  int j = c & 7;
#pragma unroll
  for (int o = 0; o < 32; ++o) {
    int mt = o >> 4;
    size_t idx = ((size_t)n * 8 + (size_t)(cb * 2 + mt)) * 512 +
                 (size_t)((lbase + (o & 15)) * 8 + j);
    _Float16 hv = (_Float16)(w2[o * 128 + c] * a);
    wAf[idx] = __builtin_bit_cast(unsigned short, hv);
  }
  if (c < 32) {
    float bb = 0.f;
    for (int q = 0; q < 128; ++q) bb += w2[c * 128 + q] * dArr[q];
    beff[n * 32 + c] = bb;
  }
}

// K3: MFMA conv2 + row softmax/cumsum epilogue. 32 KB LDS.
// XCD-chunked blockIdx swizzle (T1): each XCD gets a contiguous 512-block chunk
// so consecutive output rows (n,i),(n,i+1) -- which share a t source row -- are
// co-resident on the SAME XCD and the second read of each row-slab hits its L2.
// Round 7 evidence: default round-robin gave ZERO reuse (FETCH = 2.0x t).
__global__ __launch_bounds__(256, 5) void k3_ref(const float* __restrict__ t,
                                                 const unsigned short* __restrict__ wAf,
                                                 const float* __restrict__ beff,
                                                 float* __restrict__ refodd,
                                                 float* __restrict__ gy) {
  int blk = (blockIdx.x & 7) * 512 + (blockIdx.x >> 3);  // bijective: 4096 = 8*512
  int n = blk >> 8, i = blk & 255;
  __shared__ float smem[8192];        // 32 KB exactly
  int tid = threadIdx.x;
  float* ch = smem;                   // [0, 4096) floats (phase AB)
  char* glb = (char*)(smem + 4096);   // byte 16384, 16 KB f16 B-panel (phase AB)
  float* lmaxS = smem;                // epilogue alias (behind barrier)
  float* lsumS = smem + 64;
  const float* bn = beff + n * CO;    // uniform

  if (tid < 4) ch[4096 + tid] = 0.f;  // guard: finite bits for the x0+1 read at cc=31

  int lane = tid & 63;
  h8v wfrag[8];                       // A-frags: [cb][mt], resident all kernel
#pragma unroll
  for (int u = 0; u < 8; ++u)
    wfrag[u] = *(const h8v*)(wAf + ((size_t)n * 8 + u) * 512 + lane * 8);

  float ys = i * (127.f / 255.f);
  float y0f = floorf(ys);
  int y0 = (int)y0f, y1 = min(y0 + 1, 127);
  float wy = ys - y0f, omwy = 1.f - wy;
  float xs = tid * (127.f / 255.f);
  float x0f = floorf(xs);
  int x0 = (int)x0f;
  float wx = xs - x0f, omwx = 1.f - wx;

  f32x4 acc[2][4];
#pragma unroll
  for (int mt = 0; mt < 2; ++mt)
#pragma unroll
    for (int xt = 0; xt < 4; ++xt)
      acc[mt][xt] = (f32x4){0.f, 0.f, 0.f, 0.f};

  int wv6 = tid & 192;                // wave base pixel
  int cg = (tid >> 4) & 3;            // lane's k-granule within the B-frag
  const size_t tbase = (size_t)n * CMID * (HL * WL);

#pragma unroll
  for (int cb = 0; cb < 4; ++cb) {
    __syncthreads();                  // prev g-compute reads of ch done
    for (int f = tid; f < 32 * 32; f += 256) {
      int cc = f >> 5, x4 = (f & 31) * 4;
      const float* base = t + tbase + (size_t)(cb * 32 + cc) * (HL * WL) + x4;
      float4 a = *(const float4*)(base + y0 * WL);
      float4 b = *(const float4*)(base + y1 * WL);
      float4 cmb;
      cmb.x = fmaf(a.x, omwy, b.x * wy);
      cmb.y = fmaf(a.y, omwy, b.y * wy);
      cmb.z = fmaf(a.z, omwy, b.z * wy);
      cmb.w = fmaf(a.w, omwy, b.w * wy);
      *(float4*)&ch[cc * 128 + x4] = cmb;
    }
    __syncthreads();                  // ch ready

    unsigned gp[16];
#pragma unroll
    for (int p = 0; p < 16; ++p) {
      const float* c0 = &ch[(2 * p) * 128 + x0];
      float g0 = gelu_fast(fmaf(c0[0], omwx, c0[1] * wx));
      const float* c1 = c0 + 128;
      float g1 = gelu_fast(fmaf(c1[0], omwx, c1[1] * wx));
      h2v hv;
      hv.x = (_Float16)g0;            // RNE casts for accuracy
      hv.y = (_Float16)g1;
      gp[p] = __builtin_bit_cast(unsigned, hv);
    }
    // write this pixel's 64B B-row, 16B chunks XOR-swizzled to spread banks
    int xsw = (tid & 3) ^ ((tid >> 2) & 3);
    char* grow = glb + tid * 64;
    uint4 q;
    q.x = gp[0];  q.y = gp[1];  q.z = gp[2];  q.w = gp[3];
    *(uint4*)(grow + ((0 ^ xsw) << 4)) = q;
    q.x = gp[4];  q.y = gp[5];  q.z = gp[6];  q.w = gp[7];
    *(uint4*)(grow + ((1 ^ xsw) << 4)) = q;
    q.x = gp[8];  q.y = gp[9];  q.z = gp[10]; q.w = gp[11];
    *(uint4*)(grow + ((2 ^ xsw) << 4)) = q;
    q.x = gp[12]; q.y = gp[13]; q.z = gp[14]; q.w = gp[15];
    *(uint4*)(grow + ((3 ^ xsw) << 4)) = q;
    __syncthreads();                  // gl ready

#pragma unroll
    for (int xt = 0; xt < 4; ++xt) {
      int xrow = wv6 + xt * 16 + (tid & 15);
      int slot = cg ^ (xrow & 3) ^ ((xrow >> 2) & 3);
      h8v bfrag = *(const h8v*)(glb + xrow * 64 + (slot << 4));
      acc[0][xt] = __builtin_amdgcn_mfma_f32_16x16x32_f16(wfrag[cb * 2 + 0], bfrag,
                                                          acc[0][xt], 0, 0, 0);
      acc[1][xt] = __builtin_amdgcn_mfma_f32_16x16x32_f16(wfrag[cb * 2 + 1], bfrag,
                                                          acc[1][xt], 0, 0, 0);
    }
  }

  __syncthreads();                    // all MFMA B-reads done before smem reuse
  // D-frags -> LDS [x][o]: stride 128B, XOR-8 swizzle (conflict-minimal)
#pragma unroll
  for (int mt = 0; mt < 2; ++mt)
#pragma unroll
    for (int xt = 0; xt < 4; ++xt) {
      int xrow = wv6 + xt * 16 + (tid & 15);
      int go = mt * 4 + ((tid >> 4) & 3);   // o-chunk index (4 f32)
      *(f32x4*)((char*)smem + xrow * 128 + ((go ^ (xrow & 7)) << 4)) = acc[mt][xt];
    }
  __syncthreads();

  float accv[32];
#pragma unroll
  for (int gg = 0; gg < 8; ++gg) {
    f32x4 v = *(const f32x4*)((char*)smem + tid * 128 + ((gg ^ (tid & 7)) << 4));
    accv[4 * gg + 0] = v[0];
    accv[4 * gg + 1] = v[1];
    accv[4 * gg + 2] = v[2];
    accv[4 * gg + 3] = v[3];
  }
#pragma unroll
  for (int o = 0; o < 32; ++o) accv[o] += bn[o];

  __syncthreads();                    // accv reads done; lmaxS/lsumS may alias smem

  // odd channels -> refodd
#pragma unroll
  for (int k = 0; k < 16; ++k)
    refodd[(((size_t)(n * 16 + k)) * HO + i) * WO + tid] = accv[2 * k + 1];

  // even channels: row softmax + cumsum -> gy (batched phases).
  int lane2 = tid & 63, w = tid >> 6;
#pragma unroll
  for (int k = 0; k < 16; ++k) {
    float m = accv[2 * k];
#pragma unroll
    for (int d = 32; d; d >>= 1) m = fmaxf(m, __shfl_xor(m, d, 64));
    if (lane2 == 0) lmaxS[k * 4 + w] = m;
  }
  __syncthreads();
  float pk[16];
#pragma unroll
  for (int k = 0; k < 16; ++k) {
    float m = fmaxf(fmaxf(lmaxS[k * 4 + 0], lmaxS[k * 4 + 1]),
                    fmaxf(lmaxS[k * 4 + 2], lmaxS[k * 4 + 3]));
    float p = __expf(accv[2 * k] - m);
#pragma unroll
    for (int d = 1; d < 64; d <<= 1) {
      float q = __shfl_up(p, d, 64);
      if (lane2 >= d) p += q;
    }
    pk[k] = p;
    if (lane2 == 63) lsumS[k * 4 + w] = p;
  }
  __syncthreads();
#pragma unroll
  for (int k = 0; k < 16; ++k) {
    float off = 0.f, tot = 0.f;
#pragma unroll
    for (int q = 0; q < 4; ++q) {
      float x = lsumS[k * 4 + q];
      tot += x;
      if (q < w) off += x;
    }
    gy[((size_t)(n * 16 + k) * HO + i) * WO + tid] =
        (pk[k] + off) * (255.f * __builtin_amdgcn_rcpf(tot));
  }
}

// K5: column softmax+cumsum -> gx, in place over refodd.
__global__ __launch_bounds__(256) void k5_colscan(float* __restrict__ refodd) {
  int blk = blockIdx.x;           // nk*4 + cg
  int nk = blk >> 2, cg = blk & 3;
  int tid = threadIdx.x;
  int c = tid >> 6, j = tid & 63;
  __shared__ float lmax[4 * 64], lsum[4 * 64];
  float* img = refodd + (size_t)nk * (HO * WO) + cg * 64 + j;

  float p[64];
  float m = -1e30f;
#pragma unroll
  for (int q = 0; q < 64; ++q) {
    p[q] = img[(size_t)(c * 64 + q) * WO];
    m = fmaxf(m, p[q]);
  }
  lmax[c * 64 + j] = m;
  __syncthreads();
  m = fmaxf(fmaxf(lmax[j], lmax[64 + j]), fmaxf(lmax[128 + j], lmax[192 + j]));
  float s = 0.f;
#pragma unroll
  for (int q = 0; q < 64; ++q) {
    p[q] = __expf(p[q] - m);
    s += p[q];
  }
  lsum[c * 64 + j] = s;
  __syncthreads();
  float off = 0.f, tot = 0.f;
#pragma unroll
  for (int q2 = 0; q2 < 4; ++q2) {
    float x = lsum[q2 * 64 + j];
    tot += x;
    if (q2 < c) off += x;
  }
  float inv255 = 255.f * __builtin_amdgcn_rcpf(tot);
  float run = off;
#pragma unroll
  for (int q = 0; q < 64; ++q) {
    run += p[q];
    img[(size_t)(c * 64 + q) * WO] = run * inv255;
  }
}

// K6 v4 + XCD-chunked swizzle: the 16 tiles of one hi channel-image (256 KB)
// now land on ONE XCD (contiguous chunk) instead of scattering across 8 L2s,
// so hi gather taps hit L2. Rest unchanged from round 6.
__global__ __launch_bounds__(256, 4) void k6_sample_t4(const float* __restrict__ gx,
                                                       const float* __restrict__ hi,
                                                       float* out) {
  int blk = (blockIdx.x & 7) * 512 + (blockIdx.x >> 3);  // bijective: 4096 = 8*512
  int nk = blk >> 4, ti = (blk >> 2) & 3, tj = blk & 3;
  __shared__ float gxl[64 * 65];   // coords; becomes result tile
  __shared__ float gyl[64 * 65];
  int tid = threadIdx.x;
  const size_t ibase = (size_t)nk * (HO * WO);
  const size_t tb = ibase + (size_t)(ti * 64) * WO + tj * 64;
  const float* himg = hi + ibase;

  // Phase 0: dense coalesced stage of gx and gy (gy aliases out).
#pragma unroll
  for (int ph = 0; ph < 4; ++ph) {
    int r = ph * 16 + (tid >> 4), c4 = (tid & 15) * 4;
    float4 vx = *(const float4*)(gx + tb + (size_t)r * WO + c4);
    float4 vy = *(const float4*)(out + tb + (size_t)r * WO + c4);
    int a = r * 65 + c4;
    gxl[a] = vx.x; gxl[a + 1] = vx.y; gxl[a + 2] = vx.z; gxl[a + 3] = vx.w;
    gyl[a] = vy.x; gyl[a + 1] = vy.y; gyl[a + 2] = vy.z; gyl[a + 3] = vy.w;
  }
  __syncthreads();

  // Phase 1: thread (row il, cols jg*16..+15) reads its 32 coords from LDS
  // (lane-stride 65 -> 2-way bank alias, free) and issues ALL 64 taps.
  int il = tid & 63, jg = tid >> 6;
  const float* lgx = &gxl[il * 65 + jg * 16];
  const float* lgy = &gyl[il * 65 + jg * 16];
  float wxa[16], wya[16];
  float v00[16], v01[16], v10[16], v11[16];
#pragma unroll
  for (int s = 0; s < 16; ++s) {
    float xf = lgx[s], yf = lgy[s];
    float x0f = floorf(xf), y0f = floorf(yf);
    wxa[s] = xf - x0f; wya[s] = yf - y0f;
    int x0 = (int)x0f, y0 = (int)y0f;
    int x1 = min(x0 + 1, 255), y1 = min(y0 + 1, 255);
    const float* r0 = himg + y0 * WO;
    const float* r1 = himg + y1 * WO;
    v00[s] = r0[x0]; v01[s] = r0[x1];
    v10[s] = r1[x0]; v11[s] = r1[x1];
  }
  // Real compiler memory barrier: loads cannot sink past it.
  asm volatile("" ::: "memory");
  __syncthreads();

  // Phase 2: bilinear combine; results overwrite gxl.
  float* lrow = &gxl[il * 65 + jg * 16];
#pragma unroll
  for (int s = 0; s < 16; ++s) {
    float top = fmaf(v01[s] - v00[s], wxa[s], v00[s]);
    float bot = fmaf(v11[s] - v10[s], wxa[s], v10[s]);
    lrow[s] = fmaf(bot - top, wya[s], top);
  }
  __syncthreads();

  // Phase 3: dense store (wave covers 16 full 256B rows).
#pragma unroll
  for (int ph = 0; ph < 4; ++ph) {
    int r = ph * 16 + (tid >> 4), c4 = (tid & 15) * 4;
    int a = r * 65 + c4;
    float4 v;
    v.x = gxl[a]; v.y = gxl[a + 1]; v.z = gxl[a + 2]; v.w = gxl[a + 3];
    *(float4*)(out + tb + (size_t)r * WO + c4) = v;
  }
}

extern "C" void kernel_launch(void* const* d_in, const int* in_sizes, int n_in,
                              void* d_out, int out_size, void* d_ws, size_t ws_size,
                              hipStream_t stream) {
  (void)in_sizes; (void)n_in; (void)out_size; (void)ws_size;
  const float* lo  = (const float*)d_in[0];
  const float* hi  = (const float*)d_in[1];
  const float* w1  = (const float*)d_in[2];
  const float* b1  = (const float*)d_in[3];
  const float* gnw = (const float*)d_in[4];
  const float* gnb = (const float*)d_in[5];
  const float* sw1 = (const float*)d_in[6];
  const float* sw2 = (const float*)d_in[7];
  const float* w2  = (const float*)d_in[8];
  float* ws = (float*)d_ws;
  float* t       = ws;                    // 33,554,432 floats
  float* refodd  = ws + 33554432;         // 16,777,216 floats (becomes gx in place)
  float* S1p     = ws + 50331648;         // 8192
  float* S2p     = S1p + 8192;            // 8192
  unsigned short* wAf = (unsigned short*)(S2p + 8192);  // 65,536 f16 in old w2effT slot
  float* beff    = S2p + 8192 + 65536;    // 512
  float* w1T     = beff + 512;            // 8192
  float* out     = (float*)d_out;
  float* gybuf   = out;                   // gy aliases d_out

  k0_transpose<<<dim3(1), dim3(256), 0, stream>>>(w1, w1T);
  k1_conv1<<<dim3(2048), dim3(512), 0, stream>>>(lo, w1T, b1, t);
  k2_stats<<<dim3(8192), dim3(256), 0, stream>>>(t, S1p, S2p);
  k2b_prep<<<dim3(16), dim3(128), 0, stream>>>(S1p, S2p, gnw, gnb, sw1, sw2, w2, wAf, beff);
  k3_ref<<<dim3(4096), dim3(256), 0, stream>>>(t, wAf, beff, refodd, gybuf);
  k5_colscan<<<dim3(1024), dim3(256), 0, stream>>>(refodd);
  k6_sample_t4<<<dim3(4096), dim3(256), 0, stream>>>(refodd, hi, out);
}

// Round 9
// 615.289 us; speedup vs baseline: 1.0525x; 1.0211x over previous
//
#include <hip/hip_runtime.h>
#include <math.h>

#define N_IMG 16
#define CIN   64
#define CMID  128
#define CO    32
#define KHD   16
#define HL    128
#define WL    128
#define HO    256
#define WO    256
#define EPSV  1e-5f

typedef float f32x4 __attribute__((ext_vector_type(4)));
typedef _Float16 h8v __attribute__((ext_vector_type(8)));
typedef _Float16 h2v __attribute__((ext_vector_type(2)));

// ---------------- workspace layout (floats) ----------------
// [0, 33554432)            t (16,128,128,128)       -- dead after K3
// [33554432, 50331648)     refodd (16,16,256,256)   -- K5 overwrites in place with gx
// [50331648, +8192)        S1p (4,2048)
// [+8192, +8192)           S2p (4,2048)
// [+..., 65536 f32 slot)   wAf: f16 A-fragments (16 n x 4 cb x 2 mt x 64 lane x 8)
// [+..., 512)              beff (16,32)
// [+..., 8192)             w1T (64,128)  [c][o]
// gy lives in d_out (K6 stages its gy tile into LDS before overwriting).

// K0: transpose conv1 weights to [c][o] so K1 can read them wave-uniformly.
__global__ __launch_bounds__(256) void k0_transpose(const float* __restrict__ w1,
                                                    float* __restrict__ w1T) {
  int tid = threadIdx.x;
  for (int f = tid; f < CMID * CIN; f += 256) {
    int o = f >> 6, c = f & 63;
    w1T[c * CMID + o] = w1[f];
  }
}

// K1: t[n][o][y][x] = conv1_b[o] + sum_c conv1_w[o][c] * lo[n][c][y][x]
__global__ __launch_bounds__(512) void k1_conv1(const float* __restrict__ lo,
                                                const float* __restrict__ w1T,
                                                const float* __restrict__ b1,
                                                float* __restrict__ t) {
  int blk = blockIdx.x;        // n*128 + y
  int n = blk >> 7, y = blk & 127;
  __shared__ float lo_l[CIN * WL];    // [c][x]  32 KB
  int tid = threadIdx.x;
  const float* lo_base = lo + (size_t)n * CIN * (HL * WL) + y * WL;
  for (int f = tid; f < CIN * WL / 4; f += 512) {
    int c = f >> 5, xi = f & 31;
    ((float4*)lo_l)[f] = *(const float4*)(lo_base + (size_t)c * (HL * WL) + xi * 4);
  }
  __syncthreads();

  int wave = __builtin_amdgcn_readfirstlane(tid >> 6);  // force wave-uniform
  int lane = tid & 63;
  int half = wave >> 2;   // x-half
  int og   = wave & 3;    // 32-output group
  int x = half * 64 + lane;

  float acc[32];
#pragma unroll
  for (int o = 0; o < 32; ++o) acc[o] = 0.f;

  const float* wbase = w1T + og * 32;   // [c][o], stride CMID; uniform
  for (int c = 0; c < CIN; ++c) {
    float lv = lo_l[c * WL + x];
    const float* wr = wbase + c * CMID;
#pragma unroll
    for (int o = 0; o < 32; ++o) acc[o] += wr[o] * lv;
  }
  const float* bb = b1 + og * 32;       // uniform
  float* tb = t + ((size_t)n * CMID + og * 32) * (HL * WL) + y * WL + x;
#pragma unroll
  for (int o = 0; o < 32; ++o) tb[(size_t)o * (HL * WL)] = acc[o] + bb[o];
}

// Fast erf (A&S 7.1.26, |err| <= 1.5e-7), DIV-FREE: v_rcp instead of IEEE divide.
__device__ __forceinline__ float erf_fast(float x) {
  float ax = fabsf(x);
  float t = __builtin_amdgcn_rcpf(fmaf(0.3275911f, ax, 1.f));
  float e = __expf(-ax * ax);
  float poly = t * (0.254829592f +
              t * (-0.284496736f +
              t * (1.421413741f +
              t * (-1.453152027f +
              t * 1.061405429f))));
  float r = fmaf(-poly, e, 1.f);
  return copysignf(r, x);
}

__device__ __forceinline__ float gelu_fast(float v) {
  float h = 0.5f * v;
  return fmaf(h, erf_fast(v * 0.70710678118654752f), h);
}

// K2: per (q, n, c): partial sum & sumsq of GELU(bilinear_upsample(t[n,c]))
__global__ __launch_bounds__(256) void k2_stats(const float* __restrict__ t,
                                                float* __restrict__ S1p,
                                                float* __restrict__ S2p) {
  int blk = blockIdx.x;          // q*2048 + nc
  int nc = blk & 2047, q = blk >> 11;
  __shared__ float img[34 * WL]; // 17 KB
  __shared__ float red[16];
  int tid = threadIdx.x;
  int i0 = q * 64;
  int ylo = (int)floorf(i0 * (127.f / 255.f));
  int yhi = min((int)floorf((i0 + 63) * (127.f / 255.f)) + 1, 127);
  int nr = yhi - ylo + 1;
  const float* tb = t + (size_t)nc * (HL * WL) + ylo * WL;
  for (int f = tid; f < nr * (WL / 4); f += 256)
    ((float4*)img)[f] = ((const float4*)tb)[f];
  __syncthreads();

  float xs = tid * (127.f / 255.f);
  float x0f = floorf(xs);
  int x0 = (int)x0f, x1 = min(x0 + 1, 127);
  float wx = xs - x0f, omwx = 1.f - wx;
  float sum = 0.f, ssq = 0.f;
  for (int k = 0; k < 64; ++k) {
    float ys = (i0 + k) * (127.f / 255.f);
    float y0f = floorf(ys);
    int y0 = (int)y0f - ylo, y1 = min((int)y0f + 1, 127) - ylo;
    float wy = ys - y0f, omwy = 1.f - wy;
    float r0 = img[y0 * WL + x0] * omwx + img[y0 * WL + x1] * wx;
    float r1 = img[y1 * WL + x0] * omwx + img[y1 * WL + x1] * wx;
    float g = gelu_fast(r0 * omwy + r1 * wy);
    sum += g; ssq += g * g;
  }
  int lane = tid & 63, w = tid >> 6;
#pragma unroll
  for (int d = 32; d; d >>= 1) {
    sum += __shfl_xor(sum, d, 64);
    ssq += __shfl_xor(ssq, d, 64);
  }
  if (lane == 0) { red[w] = sum; red[8 + w] = ssq; }
  __syncthreads();
  if (tid == 0) {
    S1p[blk] = red[0] + red[1] + red[2] + red[3];
    S2p[blk] = red[8] + red[9] + red[10] + red[11];
  }
}

// K2b: fold GN + SE + conv2 into per-image effective weights + bias.
// Weights are emitted as f16 MFMA A-fragments for v_mfma_f32_16x16x32_f16:
//   A[row=o&15][k=c&31] of tile (cb=c>>5, mt=o>>4); lane = ((c&31)>>3)*16 + (o&15),
//   element j = c&7  ->  wAf[((n*4+cb)*2+mt)*512 + lane*8 + j]
__global__ __launch_bounds__(128) void k2b_prep(const float* __restrict__ S1p,
                                                const float* __restrict__ S2p,
                                                const float* __restrict__ gn_w,
                                                const float* __restrict__ gn_b,
                                                const float* __restrict__ se_w1,
                                                const float* __restrict__ se_w2,
                                                const float* __restrict__ w2,
                                                unsigned short* __restrict__ wAf,
                                                float* __restrict__ beff) {
  int n = blockIdx.x, c = threadIdx.x;
  int nc = n * 128 + c;
  __shared__ float mArr[128], eArr[128], pArr[128], hArr[16], dArr[128];
  const float inv = 1.f / 65536.f;
  float m  = (S1p[nc] + S1p[2048 + nc] + S1p[4096 + nc] + S1p[6144 + nc]) * inv;
  float e2 = (S2p[nc] + S2p[2048 + nc] + S2p[4096 + nc] + S2p[6144 + nc]) * inv;
  mArr[c] = m; eArr[c] = e2;
  __syncthreads();
  int g0 = (c >> 6) << 6;
  float mu = 0.f, E2 = 0.f;
  for (int q = 0; q < 64; ++q) { mu += mArr[g0 + q]; E2 += eArr[g0 + q]; }
  mu *= (1.f / 64.f); E2 *= (1.f / 64.f);
  float var = E2 - mu * mu;
  float rs = rsqrtf(var + EPSV);
  float gw = gn_w[c], gb = gn_b[c];
  pArr[c] = (m - mu) * rs * gw + gb;
  __syncthreads();
  if (c < 16) {
    float h = 0.f;
    for (int q = 0; q < 128; ++q) h += se_w1[c * 128 + q] * pArr[q];
    hArr[c] = fmaxf(h, 0.f);
  }
  __syncthreads();
  float sacc = 0.f;
  for (int q = 0; q < 16; ++q) sacc += se_w2[c * 16 + q] * hArr[q];
  float s = __builtin_amdgcn_rcpf(1.f + __expf(-sacc));
  float a = s * gw * rs;
  float d = s * (gb - gw * rs * mu);
  dArr[c] = d;
  __syncthreads();
  int cb = c >> 5;
  int lbase = ((c >> 3) & 3) << 4;   // (lane>>4) = (c&31)>>3
  int j = c & 7;
#pragma unroll
  for (int o = 0; o < 32; ++o) {
    int mt = o >> 4;
    size_t idx = ((size_t)n * 8 + (size_t)(cb * 2 + mt)) * 512 +
                 (size_t)((lbase + (o & 15)) * 8 + j);
    _Float16 hv = (_Float16)(w2[o * 128 + c] * a);
    wAf[idx] = __builtin_bit_cast(unsigned short, hv);
  }
  if (c < 32) {
    float bb = 0.f;
    for (int q = 0; q < 128; ++q) bb += w2[c * 128 + q] * dArr[q];
    beff[n * 32 + c] = bb;
  }
}

// K3: MFMA conv2 + row softmax/cumsum epilogue.
// LDS = ONE 16.4 KB region (was 32 KB): ch (f32 staging) and glb (f16 B-panel)
// share it IN PLACE -- the gelu phase reads all ch values into gp[] registers,
// a barrier separates everyone's reads from the panel writes. D-phase transpose
// is intra-wave (row tid is written by wave tid>>6), done in two half-phases of
// 2 waves x 8KB slots. 16.4 KB -> 8 blocks/CU (wave-slot cap) vs 39% measured
// occupancy at 32 KB. XCD-chunked swizzle retained (FETCH 279->83 MB, round 8).
__global__ __launch_bounds__(256, 6) void k3_ref(const float* __restrict__ t,
                                                 const unsigned short* __restrict__ wAf,
                                                 const float* __restrict__ beff,
                                                 float* __restrict__ refodd,
                                                 float* __restrict__ gy) {
  int blk = (blockIdx.x & 7) * 512 + (blockIdx.x >> 3);  // bijective: 4096 = 8*512
  int n = blk >> 8, i = blk & 255;
  __shared__ float smem[4100];        // 16,400 B: 4096 shared ch/glb/D + 4 guard
  int tid = threadIdx.x;
  float* ch = smem;                   // f32 [32][128] view
  char* glb = (char*)smem;            // f16 B-panel view (256 rows x 64B), same bytes
  float* lmaxS = smem;                // epilogue alias (behind barrier)
  float* lsumS = smem + 64;
  const float* bn = beff + n * CO;    // uniform

  if (tid < 4) ch[4096 + tid] = 0.f;  // guard: finite for the x0+1 read at cc=31
                                      // (bytes 16384..16399, untouched by all phases)

  int lane = tid & 63;
  h8v wfrag[8];                       // A-frags: [cb][mt], resident all kernel
#pragma unroll
  for (int u = 0; u < 8; ++u)
    wfrag[u] = *(const h8v*)(wAf + ((size_t)n * 8 + u) * 512 + lane * 8);

  float ys = i * (127.f / 255.f);
  float y0f = floorf(ys);
  int y0 = (int)y0f, y1 = min(y0 + 1, 127);
  float wy = ys - y0f, omwy = 1.f - wy;
  float xs = tid * (127.f / 255.f);
  float x0f = floorf(xs);
  int x0 = (int)x0f;
  float wx = xs - x0f, omwx = 1.f - wx;

  f32x4 acc[2][4];
#pragma unroll
  for (int mt = 0; mt < 2; ++mt)
#pragma unroll
    for (int xt = 0; xt < 4; ++xt)
      acc[mt][xt] = (f32x4){0.f, 0.f, 0.f, 0.f};

  int wv6 = tid & 192;                // wave base pixel
  int cg = (tid >> 4) & 3;            // lane's k-granule within the B-frag
  const size_t tbase = (size_t)n * CMID * (HL * WL);

#pragma unroll
  for (int cb = 0; cb < 4; ++cb) {
    __syncthreads();                  // B0: prev mfma reads of glb done
    for (int f = tid; f < 32 * 32; f += 256) {
      int cc = f >> 5, x4 = (f & 31) * 4;
      const float* base = t + tbase + (size_t)(cb * 32 + cc) * (HL * WL) + x4;
      float4 a = *(const float4*)(base + y0 * WL);
      float4 b = *(const float4*)(base + y1 * WL);
      float4 cmb;
      cmb.x = fmaf(a.x, omwy, b.x * wy);
      cmb.y = fmaf(a.y, omwy, b.y * wy);
      cmb.z = fmaf(a.z, omwy, b.z * wy);
      cmb.w = fmaf(a.w, omwy, b.w * wy);
      *(float4*)&ch[cc * 128 + x4] = cmb;
    }
    __syncthreads();                  // B1: ch ready

    unsigned gp[16];
#pragma unroll
    for (int p = 0; p < 16; ++p) {
      const float* c0 = &ch[(2 * p) * 128 + x0];
      float g0 = gelu_fast(fmaf(c0[0], omwx, c0[1] * wx));
      const float* c1 = c0 + 128;
      float g1 = gelu_fast(fmaf(c1[0], omwx, c1[1] * wx));
      h2v hv;
      hv.x = (_Float16)g0;            // RNE casts for accuracy
      hv.y = (_Float16)g1;
      gp[p] = __builtin_bit_cast(unsigned, hv);
    }
    __syncthreads();                  // B2: ALL ch reads done; region reusable

    // write this pixel's 64B B-row IN PLACE, 16B chunks XOR-swizzled
    int xsw = (tid & 3) ^ ((tid >> 2) & 3);
    char* grow = glb + tid * 64;
    uint4 q;
    q.x = gp[0];  q.y = gp[1];  q.z = gp[2];  q.w = gp[3];
    *(uint4*)(grow + ((0 ^ xsw) << 4)) = q;
    q.x = gp[4];  q.y = gp[5];  q.z = gp[6];  q.w = gp[7];
    *(uint4*)(grow + ((1 ^ xsw) << 4)) = q;
    q.x = gp[8];  q.y = gp[9];  q.z = gp[10]; q.w = gp[11];
    *(uint4*)(grow + ((2 ^ xsw) << 4)) = q;
    q.x = gp[12]; q.y = gp[13]; q.z = gp[14]; q.w = gp[15];
    *(uint4*)(grow + ((3 ^ xsw) << 4)) = q;
    __syncthreads();                  // B3: glb ready

#pragma unroll
    for (int xt = 0; xt < 4; ++xt) {
      int xrow = wv6 + xt * 16 + (tid & 15);
      int slot = cg ^ (xrow & 3) ^ ((xrow >> 2) & 3);
      h8v bfrag = *(const h8v*)(glb + xrow * 64 + (slot << 4));
      acc[0][xt] = __builtin_amdgcn_mfma_f32_16x16x32_f16(wfrag[cb * 2 + 0], bfrag,
                                                          acc[0][xt], 0, 0, 0);
      acc[1][xt] = __builtin_amdgcn_mfma_f32_16x16x32_f16(wfrag[cb * 2 + 1], bfrag,
                                                          acc[1][xt], 0, 0, 0);
    }
  }

  // D-phase: intra-wave transpose through the same region, two half-phases of
  // 2 waves x 8KB slots (stride 128B, XOR-8 swizzle). Wave wv writes rows
  // [64wv, 64wv+64); reader thread tid reads row tid -> same wave.
  float accv[32];
  int wv = tid >> 6;
#pragma unroll
  for (int phD = 0; phD < 2; ++phD) {
    __syncthreads();                  // region free (mfma/prev-phase reads done)
    if ((wv >> 1) == phD) {
      char* slotb = (char*)smem + (wv & 1) * 8192;
#pragma unroll
      for (int mt = 0; mt < 2; ++mt)
#pragma unroll
        for (int xt = 0; xt < 4; ++xt) {
          int lr = xt * 16 + (tid & 15);        // row within wave
          int go = mt * 4 + ((tid >> 4) & 3);   // o-chunk index (4 f32)
          *(f32x4*)(slotb + lr * 128 + ((go ^ (lr & 7)) << 4)) = acc[mt][xt];
        }
    }
    __syncthreads();                  // writes visible
    if ((wv >> 1) == phD) {
      char* slotb = (char*)smem + (wv & 1) * 8192;
      int lr = tid & 63;
#pragma unroll
      for (int gg = 0; gg < 8; ++gg) {
        f32x4 v = *(const f32x4*)(slotb + lr * 128 + ((gg ^ (lr & 7)) << 4));
        accv[4 * gg + 0] = v[0];
        accv[4 * gg + 1] = v[1];
        accv[4 * gg + 2] = v[2];
        accv[4 * gg + 3] = v[3];
      }
    }
  }
  __syncthreads();                    // all D reads done; lmaxS/lsumS may alias

#pragma unroll
  for (int o = 0; o < 32; ++o) accv[o] += bn[o];

  // odd channels -> refodd
#pragma unroll
  for (int k = 0; k < 16; ++k)
    refodd[(((size_t)(n * 16 + k)) * HO + i) * WO + tid] = accv[2 * k + 1];

  // even channels: row softmax + cumsum -> gy (batched phases).
  int lane2 = tid & 63, w = tid >> 6;
#pragma unroll
  for (int k = 0; k < 16; ++k) {
    float m = accv[2 * k];
#pragma unroll
    for (int d = 32; d; d >>= 1) m = fmaxf(m, __shfl_xor(m, d, 64));
    if (lane2 == 0) lmaxS[k * 4 + w] = m;
  }
  __syncthreads();
  float pk[16];
#pragma unroll
  for (int k = 0; k < 16; ++k) {
    float m = fmaxf(fmaxf(lmaxS[k * 4 + 0], lmaxS[k * 4 + 1]),
                    fmaxf(lmaxS[k * 4 + 2], lmaxS[k * 4 + 3]));
    float p = __expf(accv[2 * k] - m);
#pragma unroll
    for (int d = 1; d < 64; d <<= 1) {
      float q = __shfl_up(p, d, 64);
      if (lane2 >= d) p += q;
    }
    pk[k] = p;
    if (lane2 == 63) lsumS[k * 4 + w] = p;
  }
  __syncthreads();
#pragma unroll
  for (int k = 0; k < 16; ++k) {
    float off = 0.f, tot = 0.f;
#pragma unroll
    for (int q = 0; q < 4; ++q) {
      float x = lsumS[k * 4 + q];
      tot += x;
      if (q < w) off += x;
    }
    gy[((size_t)(n * 16 + k) * HO + i) * WO + tid] =
        (pk[k] + off) * (255.f * __builtin_amdgcn_rcpf(tot));
  }
}

// K5: column softmax+cumsum -> gx, in place over refodd.
__global__ __launch_bounds__(256) void k5_colscan(float* __restrict__ refodd) {
  int blk = blockIdx.x;           // nk*4 + cg
  int nk = blk >> 2, cg = blk & 3;
  int tid = threadIdx.x;
  int c = tid >> 6, j = tid & 63;
  __shared__ float lmax[4 * 64], lsum[4 * 64];
  float* img = refodd + (size_t)nk * (HO * WO) + cg * 64 + j;

  float p[64];
  float m = -1e30f;
#pragma unroll
  for (int q = 0; q < 64; ++q) {
    p[q] = img[(size_t)(c * 64 + q) * WO];
    m = fmaxf(m, p[q]);
  }
  lmax[c * 64 + j] = m;
  __syncthreads();
  m = fmaxf(fmaxf(lmax[j], lmax[64 + j]), fmaxf(lmax[128 + j], lmax[192 + j]));
  float s = 0.f;
#pragma unroll
  for (int q = 0; q < 64; ++q) {
    p[q] = __expf(p[q] - m);
    s += p[q];
  }
  lsum[c * 64 + j] = s;
  __syncthreads();
  float off = 0.f, tot = 0.f;
#pragma unroll
  for (int q2 = 0; q2 < 4; ++q2) {
    float x = lsum[q2 * 64 + j];
    tot += x;
    if (q2 < c) off += x;
  }
  float inv255 = 255.f * __builtin_amdgcn_rcpf(tot);
  float run = off;
#pragma unroll
  for (int q = 0; q < 64; ++q) {
    run += p[q];
    img[(size_t)(c * 64 + q) * WO] = run * inv255;
  }
}

// K6 v4 + XCD-chunked swizzle (unchanged from round 8).
__global__ __launch_bounds__(256, 4) void k6_sample_t4(const float* __restrict__ gx,
                                                       const float* __restrict__ hi,
                                                       float* out) {
  int blk = (blockIdx.x & 7) * 512 + (blockIdx.x >> 3);  // bijective: 4096 = 8*512
  int nk = blk >> 4, ti = (blk >> 2) & 3, tj = blk & 3;
  __shared__ float gxl[64 * 65];   // coords; becomes result tile
  __shared__ float gyl[64 * 65];
  int tid = threadIdx.x;
  const size_t ibase = (size_t)nk * (HO * WO);
  const size_t tb = ibase + (size_t)(ti * 64) * WO + tj * 64;
  const float* himg = hi + ibase;

  // Phase 0: dense coalesced stage of gx and gy (gy aliases out).
#pragma unroll
  for (int ph = 0; ph < 4; ++ph) {
    int r = ph * 16 + (tid >> 4), c4 = (tid & 15) * 4;
    float4 vx = *(const float4*)(gx + tb + (size_t)r * WO + c4);
    float4 vy = *(const float4*)(out + tb + (size_t)r * WO + c4);
    int a = r * 65 + c4;
    gxl[a] = vx.x; gxl[a + 1] = vx.y; gxl[a + 2] = vx.z; gxl[a + 3] = vx.w;
    gyl[a] = vy.x; gyl[a + 1] = vy.y; gyl[a + 2] = vy.z; gyl[a + 3] = vy.w;
  }
  __syncthreads();

  // Phase 1: thread (row il, cols jg*16..+15) reads its 32 coords from LDS
  // (lane-stride 65 -> 2-way bank alias, free) and issues ALL 64 taps.
  int il = tid & 63, jg = tid >> 6;
  const float* lgx = &gxl[il * 65 + jg * 16];
  const float* lgy = &gyl[il * 65 + jg * 16];
  float wxa[16], wya[16];
  float v00[16], v01[16], v10[16], v11[16];
#pragma unroll
  for (int s = 0; s < 16; ++s) {
    float xf = lgx[s], yf = lgy[s];
    float x0f = floorf(xf), y0f = floorf(yf);
    wxa[s] = xf - x0f; wya[s] = yf - y0f;
    int x0 = (int)x0f, y0 = (int)y0f;
    int x1 = min(x0 + 1, 255), y1 = min(y0 + 1, 255);
    const float* r0 = himg + y0 * WO;
    const float* r1 = himg + y1 * WO;
    v00[s] = r0[x0]; v01[s] = r0[x1];
    v10[s] = r1[x0]; v11[s] = r1[x1];
  }
  // Real compiler memory barrier: loads cannot sink past it.
  asm volatile("" ::: "memory");
  __syncthreads();

  // Phase 2: bilinear combine; results overwrite gxl.
  float* lrow = &gxl[il * 65 + jg * 16];
#pragma unroll
  for (int s = 0; s < 16; ++s) {
    float top = fmaf(v01[s] - v00[s], wxa[s], v00[s]);
    float bot = fmaf(v11[s] - v10[s], wxa[s], v10[s]);
    lrow[s] = fmaf(bot - top, wya[s], top);
  }
  __syncthreads();

  // Phase 3: dense store (wave covers 16 full 256B rows).
#pragma unroll
  for (int ph = 0; ph < 4; ++ph) {
    int r = ph * 16 + (tid >> 4), c4 = (tid & 15) * 4;
    int a = r * 65 + c4;
    float4 v;
    v.x = gxl[a]; v.y = gxl[a + 1]; v.z = gxl[a + 2]; v.w = gxl[a + 3];
    *(float4*)(out + tb + (size_t)r * WO + c4) = v;
  }
}

extern "C" void kernel_launch(void* const* d_in, const int* in_sizes, int n_in,
                              void* d_out, int out_size, void* d_ws, size_t ws_size,
                              hipStream_t stream) {
  (void)in_sizes; (void)n_in; (void)out_size; (void)ws_size;
  const float* lo  = (const float*)d_in[0];
  const float* hi  = (const float*)d_in[1];
  const float* w1  = (const float*)d_in[2];
  const float* b1  = (const float*)d_in[3];
  const float* gnw = (const float*)d_in[4];
  const float* gnb = (const float*)d_in[5];
  const float* sw1 = (const float*)d_in[6];
  const float* sw2 = (const float*)d_in[7];
  const float* w2  = (const float*)d_in[8];
  float* ws = (float*)d_ws;
  float* t       = ws;                    // 33,554,432 floats
  float* refodd  = ws + 33554432;         // 16,777,216 floats (becomes gx in place)
  float* S1p     = ws + 50331648;         // 8192
  float* S2p     = S1p + 8192;            // 8192
  unsigned short* wAf = (unsigned short*)(S2p + 8192);  // 65,536 f16 in old w2effT slot
  float* beff    = S2p + 8192 + 65536;    // 512
  float* w1T     = beff + 512;            // 8192
  float* out     = (float*)d_out;
  float* gybuf   = out;                   // gy aliases d_out

  k0_transpose<<<dim3(1), dim3(256), 0, stream>>>(w1, w1T);
  k1_conv1<<<dim3(2048), dim3(512), 0, stream>>>(lo, w1T, b1, t);
  k2_stats<<<dim3(8192), dim3(256), 0, stream>>>(t, S1p, S2p);
  k2b_prep<<<dim3(16), dim3(128), 0, stream>>>(S1p, S2p, gnw, gnb, sw1, sw2, w2, wAf, beff);
  k3_ref<<<dim3(4096), dim3(256), 0, stream>>>(t, wAf, beff, refodd, gybuf);
  k5_colscan<<<dim3(1024), dim3(256), 0, stream>>>(refodd);
  k6_sample_t4<<<dim3(4096), dim3(256), 0, stream>>>(refodd, hi, out);
}

// Round 10
// 601.379 us; speedup vs baseline: 1.0769x; 1.0231x over previous
//
#include <hip/hip_runtime.h>
#include <math.h>

#define N_IMG 16
#define CIN   64
#define CMID  128
#define CO    32
#define KHD   16
#define HL    128
#define WL    128
#define HO    256
#define WO    256
#define EPSV  1e-5f

typedef float f32x4 __attribute__((ext_vector_type(4)));
typedef _Float16 h8v __attribute__((ext_vector_type(8)));
typedef _Float16 h2v __attribute__((ext_vector_type(2)));

// ---------------- workspace layout (floats) ----------------
// [0, 33554432)            t (16,128,128,128)       -- dead after K3
// [33554432, 50331648)     refodd (16,16,256,256)   -- K5 overwrites in place with gx
// [50331648, +8192)        S1p (4,2048)
// [+8192, +8192)           S2p (4,2048)
// [+..., 65536 f32 slot)   wAf: f16 A-fragments (16 n x 4 cb x 2 mt x 64 lane x 8)
// [+..., 512)              beff (16,32)
// [+..., 8192)             w1T (64,128)  [c][o]
// gy lives in d_out (K6 stages its gy tile into LDS before overwriting).

// K0: transpose conv1 weights to [c][o] so K1 can read them wave-uniformly.
__global__ __launch_bounds__(256) void k0_transpose(const float* __restrict__ w1,
                                                    float* __restrict__ w1T) {
  int tid = threadIdx.x;
  for (int f = tid; f < CMID * CIN; f += 256) {
    int o = f >> 6, c = f & 63;
    w1T[c * CMID + o] = w1[f];
  }
}

// K1: t[n][o][y][x] = conv1_b[o] + sum_c conv1_w[o][c] * lo[n][c][y][x]
__global__ __launch_bounds__(512) void k1_conv1(const float* __restrict__ lo,
                                                const float* __restrict__ w1T,
                                                const float* __restrict__ b1,
                                                float* __restrict__ t) {
  int blk = blockIdx.x;        // n*128 + y
  int n = blk >> 7, y = blk & 127;
  __shared__ float lo_l[CIN * WL];    // [c][x]  32 KB
  int tid = threadIdx.x;
  const float* lo_base = lo + (size_t)n * CIN * (HL * WL) + y * WL;
  for (int f = tid; f < CIN * WL / 4; f += 512) {
    int c = f >> 5, xi = f & 31;
    ((float4*)lo_l)[f] = *(const float4*)(lo_base + (size_t)c * (HL * WL) + xi * 4);
  }
  __syncthreads();

  int wave = __builtin_amdgcn_readfirstlane(tid >> 6);  // force wave-uniform
  int lane = tid & 63;
  int half = wave >> 2;   // x-half
  int og   = wave & 3;    // 32-output group
  int x = half * 64 + lane;

  float acc[32];
#pragma unroll
  for (int o = 0; o < 32; ++o) acc[o] = 0.f;

  const float* wbase = w1T + og * 32;   // [c][o], stride CMID; uniform
  for (int c = 0; c < CIN; ++c) {
    float lv = lo_l[c * WL + x];
    const float* wr = wbase + c * CMID;
#pragma unroll
    for (int o = 0; o < 32; ++o) acc[o] += wr[o] * lv;
  }
  const float* bb = b1 + og * 32;       // uniform
  float* tb = t + ((size_t)n * CMID + og * 32) * (HL * WL) + y * WL + x;
#pragma unroll
  for (int o = 0; o < 32; ++o) tb[(size_t)o * (HL * WL)] = acc[o] + bb[o];
}

// Fast erf (A&S 7.1.26, |err| <= 1.5e-7), DIV-FREE: v_rcp instead of IEEE divide.
__device__ __forceinline__ float erf_fast(float x) {
  float ax = fabsf(x);
  float t = __builtin_amdgcn_rcpf(fmaf(0.3275911f, ax, 1.f));
  float e = __expf(-ax * ax);
  float poly = t * (0.254829592f +
              t * (-0.284496736f +
              t * (1.421413741f +
              t * (-1.453152027f +
              t * 1.061405429f))));
  float r = fmaf(-poly, e, 1.f);
  return copysignf(r, x);
}

__device__ __forceinline__ float gelu_fast(float v) {
  float h = 0.5f * v;
  return fmaf(h, erf_fast(v * 0.70710678118654752f), h);
}

// K2 (templated on Q): per (n,c): partial sum & sumsq of GELU(upsample(t[n,c]))
// over output rows [Q*64, Q*64+64). The whole y-schedule y0=floor(i*127/255),
// wy, and the row-advance pattern are COMPILE-TIME (Q is a template arg), so:
//  - no runtime floorf/min/int-cast per iteration,
//  - each staged source row is x-interpolated exactly ONCE into a rolling
//    register pair (cur0,cur1) -- 33 interps instead of 128 per thread,
//  - per output pixel: 1 const-weight fma + gelu + sum/ssq.
// Round 9 evidence: k2 was pure-VALU-bound (VALUBusy ~110%, HBM 6%).
template <int Q>
__global__ __launch_bounds__(256) void k2_statsT(const float* __restrict__ t,
                                                 float* __restrict__ S1p,
                                                 float* __restrict__ S2p) {
  constexpr int I0  = Q * 64;
  constexpr int YLO = (I0 * 127) / 255;
  constexpr int YHI0 = ((I0 + 63) * 127) / 255 + 1;
  constexpr int YHI = (YHI0 > 127) ? 127 : YHI0;
  constexpr int NR  = YHI - YLO + 1;            // 33 or 34
  int nc = blockIdx.x;                          // 2048 blocks
  __shared__ float img[NR * WL];
  __shared__ float red[16];
  int tid = threadIdx.x;
  const float* tb = t + (size_t)nc * (HL * WL) + YLO * WL;
  for (int f = tid; f < NR * (WL / 4); f += 256)
    ((float4*)img)[f] = ((const float4*)tb)[f];
  __syncthreads();

  float xs = tid * (127.f / 255.f);
  float x0f = floorf(xs);
  int x0 = (int)x0f, x1 = min(x0 + 1, 127);
  float wx = xs - x0f, omwx = 1.f - wx;

  auto xv = [&](int r) {
    return img[r * WL + x0] * omwx + img[r * WL + x1] * wx;
  };

  float sum = 0.f, ssq = 0.f;
  float cur0 = xv(0);                  // row y0(I0) == YLO
  float cur1 = xv(1);                  // NR >= 2 always
#pragma unroll
  for (int k = 0; k < 64; ++k) {
    const int i = I0 + k;
    const int y0k = (i * 127) / 255;                 // compile-time
    if (k > 0 && y0k != ((i - 1) * 127) / 255) {     // static advance
      cur0 = cur1;
      if (y0k + 1 <= YHI) cur1 = xv(y0k + 1 - YLO);
    }
    const float wyk = (float)(i * 127 - 255 * y0k) * (1.f / 255.f);  // exact
    float v = (y0k + 1 <= YHI) ? fmaf(cur0, 1.f - wyk, cur1 * wyk)
                               : cur0;               // i==255: wy==0
    float g = gelu_fast(v);
    sum += g; ssq += g * g;
  }
  int lane = tid & 63, w = tid >> 6;
#pragma unroll
  for (int d = 32; d; d >>= 1) {
    sum += __shfl_xor(sum, d, 64);
    ssq += __shfl_xor(ssq, d, 64);
  }
  if (lane == 0) { red[w] = sum; red[8 + w] = ssq; }
  __syncthreads();
  if (tid == 0) {
    S1p[Q * 2048 + nc] = red[0] + red[1] + red[2] + red[3];
    S2p[Q * 2048 + nc] = red[8] + red[9] + red[10] + red[11];
  }
}

// K2b: fold GN + SE + conv2 into per-image effective weights + bias.
// Weights are emitted as f16 MFMA A-fragments for v_mfma_f32_16x16x32_f16:
//   A[row=o&15][k=c&31] of tile (cb=c>>5, mt=o>>4); lane = ((c&31)>>3)*16 + (o&15),
//   element j = c&7  ->  wAf[((n*4+cb)*2+mt)*512 + lane*8 + j]
__global__ __launch_bounds__(128) void k2b_prep(const float* __restrict__ S1p,
                                                const float* __restrict__ S2p,
                                                const float* __restrict__ gn_w,
                                                const float* __restrict__ gn_b,
                                                const float* __restrict__ se_w1,
                                                const float* __restrict__ se_w2,
                                                const float* __restrict__ w2,
                                                unsigned short* __restrict__ wAf,
                                                float* __restrict__ beff) {
  int n = blockIdx.x, c = threadIdx.x;
  int nc = n * 128 + c;
  __shared__ float mArr[128], eArr[128], pArr[128], hArr[16], dArr[128];
  const float inv = 1.f / 65536.f;
  float m  = (S1p[nc] + S1p[2048 + nc] + S1p[4096 + nc] + S1p[6144 + nc]) * inv;
  float e2 = (S2p[nc] + S2p[2048 + nc] + S2p[4096 + nc] + S2p[6144 + nc]) * inv;
  mArr[c] = m; eArr[c] = e2;
  __syncthreads();
  int g0 = (c >> 6) << 6;
  float mu = 0.f, E2 = 0.f;
  for (int q = 0; q < 64; ++q) { mu += mArr[g0 + q]; E2 += eArr[g0 + q]; }
  mu *= (1.f / 64.f); E2 *= (1.f / 64.f);
  float var = E2 - mu * mu;
  float rs = rsqrtf(var + EPSV);
  float gw = gn_w[c], gb = gn_b[c];
  pArr[c] = (m - mu) * rs * gw + gb;
  __syncthreads();
  if (c < 16) {
    float h = 0.f;
    for (int q = 0; q < 128; ++q) h += se_w1[c * 128 + q] * pArr[q];
    hArr[c] = fmaxf(h, 0.f);
  }
  __syncthreads();
  float sacc = 0.f;
  for (int q = 0; q < 16; ++q) sacc += se_w2[c * 16 + q] * hArr[q];
  float s = __builtin_amdgcn_rcpf(1.f + __expf(-sacc));
  float a = s * gw * rs;
  float d = s * (gb - gw * rs * mu);
  dArr[c] = d;
  __syncthreads();
  int cb = c >> 5;
  int lbase = ((c >> 3) & 3) << 4;   // (lane>>4) = (c&31)>>3
  int j = c & 7;
#pragma unroll
  for (int o = 0; o < 32; ++o) {
    int mt = o >> 4;
    size_t idx = ((size_t)n * 8 + (size_t)(cb * 2 + mt)) * 512 +
                 (size_t)((lbase + (o & 15)) * 8 + j);
    _Float16 hv = (_Float16)(w2[o * 128 + c] * a);
    wAf[idx] = __builtin_bit_cast(unsigned short, hv);
  }
  if (c < 32) {
    float bb = 0.f;
    for (int q = 0; q < 128; ++q) bb += w2[c * 128 + q] * dArr[q];
    beff[n * 32 + c] = bb;
  }
}

// K3: MFMA conv2 + row softmax/cumsum epilogue. One 16.4 KB LDS region
// (ch/glb/D-phase share in place), XCD-chunked swizzle. Unchanged from round 9.
__global__ __launch_bounds__(256, 6) void k3_ref(const float* __restrict__ t,
                                                 const unsigned short* __restrict__ wAf,
                                                 const float* __restrict__ beff,
                                                 float* __restrict__ refodd,
                                                 float* __restrict__ gy) {
  int blk = (blockIdx.x & 7) * 512 + (blockIdx.x >> 3);  // bijective: 4096 = 8*512
  int n = blk >> 8, i = blk & 255;
  __shared__ float smem[4100];        // 16,400 B: 4096 shared ch/glb/D + 4 guard
  int tid = threadIdx.x;
  float* ch = smem;                   // f32 [32][128] view
  char* glb = (char*)smem;            // f16 B-panel view (256 rows x 64B), same bytes
  float* lmaxS = smem;                // epilogue alias (behind barrier)
  float* lsumS = smem + 64;
  const float* bn = beff + n * CO;    // uniform

  if (tid < 4) ch[4096 + tid] = 0.f;  // guard: finite for the x0+1 read at cc=31

  int lane = tid & 63;
  h8v wfrag[8];                       // A-frags: [cb][mt], resident all kernel
#pragma unroll
  for (int u = 0; u < 8; ++u)
    wfrag[u] = *(const h8v*)(wAf + ((size_t)n * 8 + u) * 512 + lane * 8);

  float ys = i * (127.f / 255.f);
  float y0f = floorf(ys);
  int y0 = (int)y0f, y1 = min(y0 + 1, 127);
  float wy = ys - y0f, omwy = 1.f - wy;
  float xs = tid * (127.f / 255.f);
  float x0f = floorf(xs);
  int x0 = (int)x0f;
  float wx = xs - x0f, omwx = 1.f - wx;

  f32x4 acc[2][4];
#pragma unroll
  for (int mt = 0; mt < 2; ++mt)
#pragma unroll
    for (int xt = 0; xt < 4; ++xt)
      acc[mt][xt] = (f32x4){0.f, 0.f, 0.f, 0.f};

  int wv6 = tid & 192;                // wave base pixel
  int cg = (tid >> 4) & 3;            // lane's k-granule within the B-frag
  const size_t tbase = (size_t)n * CMID * (HL * WL);

#pragma unroll
  for (int cb = 0; cb < 4; ++cb) {
    __syncthreads();                  // B0: prev mfma reads of glb done
    for (int f = tid; f < 32 * 32; f += 256) {
      int cc = f >> 5, x4 = (f & 31) * 4;
      const float* base = t + tbase + (size_t)(cb * 32 + cc) * (HL * WL) + x4;
      float4 a = *(const float4*)(base + y0 * WL);
      float4 b = *(const float4*)(base + y1 * WL);
      float4 cmb;
      cmb.x = fmaf(a.x, omwy, b.x * wy);
      cmb.y = fmaf(a.y, omwy, b.y * wy);
      cmb.z = fmaf(a.z, omwy, b.z * wy);
      cmb.w = fmaf(a.w, omwy, b.w * wy);
      *(float4*)&ch[cc * 128 + x4] = cmb;
    }
    __syncthreads();                  // B1: ch ready

    unsigned gp[16];
#pragma unroll
    for (int p = 0; p < 16; ++p) {
      const float* c0 = &ch[(2 * p) * 128 + x0];
      float g0 = gelu_fast(fmaf(c0[0], omwx, c0[1] * wx));
      const float* c1 = c0 + 128;
      float g1 = gelu_fast(fmaf(c1[0], omwx, c1[1] * wx));
      h2v hv;
      hv.x = (_Float16)g0;            // RNE casts for accuracy
      hv.y = (_Float16)g1;
      gp[p] = __builtin_bit_cast(unsigned, hv);
    }
    __syncthreads();                  // B2: ALL ch reads done; region reusable

    // write this pixel's 64B B-row IN PLACE, 16B chunks XOR-swizzled
    int xsw = (tid & 3) ^ ((tid >> 2) & 3);
    char* grow = glb + tid * 64;
    uint4 q;
    q.x = gp[0];  q.y = gp[1];  q.z = gp[2];  q.w = gp[3];
    *(uint4*)(grow + ((0 ^ xsw) << 4)) = q;
    q.x = gp[4];  q.y = gp[5];  q.z = gp[6];  q.w = gp[7];
    *(uint4*)(grow + ((1 ^ xsw) << 4)) = q;
    q.x = gp[8];  q.y = gp[9];  q.z = gp[10]; q.w = gp[11];
    *(uint4*)(grow + ((2 ^ xsw) << 4)) = q;
    q.x = gp[12]; q.y = gp[13]; q.z = gp[14]; q.w = gp[15];
    *(uint4*)(grow + ((3 ^ xsw) << 4)) = q;
    __syncthreads();                  // B3: glb ready

#pragma unroll
    for (int xt = 0; xt < 4; ++xt) {
      int xrow = wv6 + xt * 16 + (tid & 15);
      int slot = cg ^ (xrow & 3) ^ ((xrow >> 2) & 3);
      h8v bfrag = *(const h8v*)(glb + xrow * 64 + (slot << 4));
      acc[0][xt] = __builtin_amdgcn_mfma_f32_16x16x32_f16(wfrag[cb * 2 + 0], bfrag,
                                                          acc[0][xt], 0, 0, 0);
      acc[1][xt] = __builtin_amdgcn_mfma_f32_16x16x32_f16(wfrag[cb * 2 + 1], bfrag,
                                                          acc[1][xt], 0, 0, 0);
    }
  }

  // D-phase: intra-wave transpose through the same region, two half-phases of
  // 2 waves x 8KB slots (stride 128B, XOR-8 swizzle).
  float accv[32];
  int wv = tid >> 6;
#pragma unroll
  for (int phD = 0; phD < 2; ++phD) {
    __syncthreads();                  // region free (mfma/prev-phase reads done)
    if ((wv >> 1) == phD) {
      char* slotb = (char*)smem + (wv & 1) * 8192;
#pragma unroll
      for (int mt = 0; mt < 2; ++mt)
#pragma unroll
        for (int xt = 0; xt < 4; ++xt) {
          int lr = xt * 16 + (tid & 15);        // row within wave
          int go = mt * 4 + ((tid >> 4) & 3);   // o-chunk index (4 f32)
          *(f32x4*)(slotb + lr * 128 + ((go ^ (lr & 7)) << 4)) = acc[mt][xt];
        }
    }
    __syncthreads();                  // writes visible
    if ((wv >> 1) == phD) {
      char* slotb = (char*)smem + (wv & 1) * 8192;
      int lr = tid & 63;
#pragma unroll
      for (int gg = 0; gg < 8; ++gg) {
        f32x4 v = *(const f32x4*)(slotb + lr * 128 + ((gg ^ (lr & 7)) << 4));
        accv[4 * gg + 0] = v[0];
        accv[4 * gg + 1] = v[1];
        accv[4 * gg + 2] = v[2];
        accv[4 * gg + 3] = v[3];
      }
    }
  }
  __syncthreads();                    // all D reads done; lmaxS/lsumS may alias

#pragma unroll
  for (int o = 0; o < 32; ++o) accv[o] += bn[o];

  // odd channels -> refodd
#pragma unroll
  for (int k = 0; k < 16; ++k)
    refodd[(((size_t)(n * 16 + k)) * HO + i) * WO + tid] = accv[2 * k + 1];

  // even channels: row softmax + cumsum -> gy (batched phases).
  int lane2 = tid & 63, w = tid >> 6;
#pragma unroll
  for (int k = 0; k < 16; ++k) {
    float m = accv[2 * k];
#pragma unroll
    for (int d = 32; d; d >>= 1) m = fmaxf(m, __shfl_xor(m, d, 64));
    if (lane2 == 0) lmaxS[k * 4 + w] = m;
  }
  __syncthreads();
  float pk[16];
#pragma unroll
  for (int k = 0; k < 16; ++k) {
    float m = fmaxf(fmaxf(lmaxS[k * 4 + 0], lmaxS[k * 4 + 1]),
                    fmaxf(lmaxS[k * 4 + 2], lmaxS[k * 4 + 3]));
    float p = __expf(accv[2 * k] - m);
#pragma unroll
    for (int d = 1; d < 64; d <<= 1) {
      float q = __shfl_up(p, d, 64);
      if (lane2 >= d) p += q;
    }
    pk[k] = p;
    if (lane2 == 63) lsumS[k * 4 + w] = p;
  }
  __syncthreads();
#pragma unroll
  for (int k = 0; k < 16; ++k) {
    float off = 0.f, tot = 0.f;
#pragma unroll
    for (int q = 0; q < 4; ++q) {
      float x = lsumS[k * 4 + q];
      tot += x;
      if (q < w) off += x;
    }
    gy[((size_t)(n * 16 + k) * HO + i) * WO + tid] =
        (pk[k] + off) * (255.f * __builtin_amdgcn_rcpf(tot));
  }
}

// K5: column softmax+cumsum -> gx, in place over refodd.
__global__ __launch_bounds__(256) void k5_colscan(float* __restrict__ refodd) {
  int blk = blockIdx.x;           // nk*4 + cg
  int nk = blk >> 2, cg = blk & 3;
  int tid = threadIdx.x;
  int c = tid >> 6, j = tid & 63;
  __shared__ float lmax[4 * 64], lsum[4 * 64];
  float* img = refodd + (size_t)nk * (HO * WO) + cg * 64 + j;

  float p[64];
  float m = -1e30f;
#pragma unroll
  for (int q = 0; q < 64; ++q) {
    p[q] = img[(size_t)(c * 64 + q) * WO];
    m = fmaxf(m, p[q]);
  }
  lmax[c * 64 + j] = m;
  __syncthreads();
  m = fmaxf(fmaxf(lmax[j], lmax[64 + j]), fmaxf(lmax[128 + j], lmax[192 + j]));
  float s = 0.f;
#pragma unroll
  for (int q = 0; q < 64; ++q) {
    p[q] = __expf(p[q] - m);
    s += p[q];
  }
  lsum[c * 64 + j] = s;
  __syncthreads();
  float off = 0.f, tot = 0.f;
#pragma unroll
  for (int q2 = 0; q2 < 4; ++q2) {
    float x = lsum[q2 * 64 + j];
    tot += x;
    if (q2 < c) off += x;
  }
  float inv255 = 255.f * __builtin_amdgcn_rcpf(tot);
  float run = off;
#pragma unroll
  for (int q = 0; q < 64; ++q) {
    run += p[q];
    img[(size_t)(c * 64 + q) * WO] = run * inv255;
  }
}

// K6 v4 + XCD-chunked swizzle (unchanged from round 9).
__global__ __launch_bounds__(256, 4) void k6_sample_t4(const float* __restrict__ gx,
                                                       const float* __restrict__ hi,
                                                       float* out) {
  int blk = (blockIdx.x & 7) * 512 + (blockIdx.x >> 3);  // bijective: 4096 = 8*512
  int nk = blk >> 4, ti = (blk >> 2) & 3, tj = blk & 3;
  __shared__ float gxl[64 * 65];   // coords; becomes result tile
  __shared__ float gyl[64 * 65];
  int tid = threadIdx.x;
  const size_t ibase = (size_t)nk * (HO * WO);
  const size_t tb = ibase + (size_t)(ti * 64) * WO + tj * 64;
  const float* himg = hi + ibase;

  // Phase 0: dense coalesced stage of gx and gy (gy aliases out).
#pragma unroll
  for (int ph = 0; ph < 4; ++ph) {
    int r = ph * 16 + (tid >> 4), c4 = (tid & 15) * 4;
    float4 vx = *(const float4*)(gx + tb + (size_t)r * WO + c4);
    float4 vy = *(const float4*)(out + tb + (size_t)r * WO + c4);
    int a = r * 65 + c4;
    gxl[a] = vx.x; gxl[a + 1] = vx.y; gxl[a + 2] = vx.z; gxl[a + 3] = vx.w;
    gyl[a] = vy.x; gyl[a + 1] = vy.y; gyl[a + 2] = vy.z; gyl[a + 3] = vy.w;
  }
  __syncthreads();

  // Phase 1: thread (row il, cols jg*16..+15) reads its 32 coords from LDS
  // (lane-stride 65 -> 2-way bank alias, free) and issues ALL 64 taps.
  int il = tid & 63, jg = tid >> 6;
  const float* lgx = &gxl[il * 65 + jg * 16];
  const float* lgy = &gyl[il * 65 + jg * 16];
  float wxa[16], wya[16];
  float v00[16], v01[16], v10[16], v11[16];
#pragma unroll
  for (int s = 0; s < 16; ++s) {
    float xf = lgx[s], yf = lgy[s];
    float x0f = floorf(xf), y0f = floorf(yf);
    wxa[s] = xf - x0f; wya[s] = yf - y0f;
    int x0 = (int)x0f, y0 = (int)y0f;
    int x1 = min(x0 + 1, 255), y1 = min(y0 + 1, 255);
    const float* r0 = himg + y0 * WO;
    const float* r1 = himg + y1 * WO;
    v00[s] = r0[x0]; v01[s] = r0[x1];
    v10[s] = r1[x0]; v11[s] = r1[x1];
  }
  // Real compiler memory barrier: loads cannot sink past it.
  asm volatile("" ::: "memory");
  __syncthreads();

  // Phase 2: bilinear combine; results overwrite gxl.
  float* lrow = &gxl[il * 65 + jg * 16];
#pragma unroll
  for (int s = 0; s < 16; ++s) {
    float top = fmaf(v01[s] - v00[s], wxa[s], v00[s]);
    float bot = fmaf(v11[s] - v10[s], wxa[s], v10[s]);
    lrow[s] = fmaf(bot - top, wya[s], top);
  }
  __syncthreads();

  // Phase 3: dense store (wave covers 16 full 256B rows).
#pragma unroll
  for (int ph = 0; ph < 4; ++ph) {
    int r = ph * 16 + (tid >> 4), c4 = (tid & 15) * 4;
    int a = r * 65 + c4;
    float4 v;
    v.x = gxl[a]; v.y = gxl[a + 1]; v.z = gxl[a + 2]; v.w = gxl[a + 3];
    *(float4*)(out + tb + (size_t)r * WO + c4) = v;
  }
}

extern "C" void kernel_launch(void* const* d_in, const int* in_sizes, int n_in,
                              void* d_out, int out_size, void* d_ws, size_t ws_size,
                              hipStream_t stream) {
  (void)in_sizes; (void)n_in; (void)out_size; (void)ws_size;
  const float* lo  = (const float*)d_in[0];
  const float* hi  = (const float*)d_in[1];
  const float* w1  = (const float*)d_in[2];
  const float* b1  = (const float*)d_in[3];
  const float* gnw = (const float*)d_in[4];
  const float* gnb = (const float*)d_in[5];
  const float* sw1 = (const float*)d_in[6];
  const float* sw2 = (const float*)d_in[7];
  const float* w2  = (const float*)d_in[8];
  float* ws = (float*)d_ws;
  float* t       = ws;                    // 33,554,432 floats
  float* refodd  = ws + 33554432;         // 16,777,216 floats (becomes gx in place)
  float* S1p     = ws + 50331648;         // 8192
  float* S2p     = S1p + 8192;            // 8192
  unsigned short* wAf = (unsigned short*)(S2p + 8192);  // 65,536 f16 in old w2effT slot
  float* beff    = S2p + 8192 + 65536;    // 512
  float* w1T     = beff + 512;            // 8192
  float* out     = (float*)d_out;
  float* gybuf   = out;                   // gy aliases d_out

  k0_transpose<<<dim3(1), dim3(256), 0, stream>>>(w1, w1T);
  k1_conv1<<<dim3(2048), dim3(512), 0, stream>>>(lo, w1T, b1, t);
  k2_statsT<0><<<dim3(2048), dim3(256), 0, stream>>>(t, S1p, S2p);
  k2_statsT<1><<<dim3(2048), dim3(256), 0, stream>>>(t, S1p, S2p);
  k2_statsT<2><<<dim3(2048), dim3(256), 0, stream>>>(t, S1p, S2p);
  k2_statsT<3><<<dim3(2048), dim3(256), 0, stream>>>(t, S1p, S2p);
  k2b_prep<<<dim3(16), dim3(128), 0, stream>>>(S1p, S2p, gnw, gnb, sw1, sw2, w2, wAf, beff);
  k3_ref<<<dim3(4096), dim3(256), 0, stream>>>(t, wAf, beff, refodd, gybuf);
  k5_colscan<<<dim3(1024), dim3(256), 0, stream>>>(refodd);
  k6_sample_t4<<<dim3(4096), dim3(256), 0, stream>>>(refodd, hi, out);
}

// Round 11
// 583.582 us; speedup vs baseline: 1.1097x; 1.0305x over previous
//
#include <hip/hip_runtime.h>
#include <math.h>

#define N_IMG 16
#define CIN   64
#define CMID  128
#define CO    32
#define KHD   16
#define HL    128
#define WL    128
#define HO    256
#define WO    256
#define EPSV  1e-5f

typedef float f32x4 __attribute__((ext_vector_type(4)));
typedef _Float16 h8v __attribute__((ext_vector_type(8)));
typedef _Float16 h2v __attribute__((ext_vector_type(2)));

// ---------------- workspace layout (floats) ----------------
// [0, 33554432)            t (16,128,128,128)       -- dead after K3
// [33554432, 50331648)     refodd (16,16,256,256)   -- K5 overwrites in place with gx
// [50331648, +8192)        S1p (4,2048)
// [+8192, +8192)           S2p (4,2048)
// [+..., 65536 f32 slot)   wAf: f16 A-fragments (16 n x 4 cb x 2 mt x 64 lane x 8)
// [+..., 512)              beff (16,32)
// [+..., 8192)             w1T (64,128)  [c][o]
// gy lives in d_out (K6 stages its gy tile into LDS before overwriting).

// K0: transpose conv1 weights to [c][o] so K1 can read them wave-uniformly.
__global__ __launch_bounds__(256) void k0_transpose(const float* __restrict__ w1,
                                                    float* __restrict__ w1T) {
  int tid = threadIdx.x;
  for (int f = tid; f < CMID * CIN; f += 256) {
    int o = f >> 6, c = f & 63;
    w1T[c * CMID + o] = w1[f];
  }
}

// K1: t[n][o][y][x] = conv1_b[o] + sum_c conv1_w[o][c] * lo[n][c][y][x]
__global__ __launch_bounds__(512) void k1_conv1(const float* __restrict__ lo,
                                                const float* __restrict__ w1T,
                                                const float* __restrict__ b1,
                                                float* __restrict__ t) {
  int blk = blockIdx.x;        // n*128 + y
  int n = blk >> 7, y = blk & 127;
  __shared__ float lo_l[CIN * WL];    // [c][x]  32 KB
  int tid = threadIdx.x;
  const float* lo_base = lo + (size_t)n * CIN * (HL * WL) + y * WL;
  for (int f = tid; f < CIN * WL / 4; f += 512) {
    int c = f >> 5, xi = f & 31;
    ((float4*)lo_l)[f] = *(const float4*)(lo_base + (size_t)c * (HL * WL) + xi * 4);
  }
  __syncthreads();

  int wave = __builtin_amdgcn_readfirstlane(tid >> 6);  // force wave-uniform
  int lane = tid & 63;
  int half = wave >> 2;   // x-half
  int og   = wave & 3;    // 32-output group
  int x = half * 64 + lane;

  float acc[32];
#pragma unroll
  for (int o = 0; o < 32; ++o) acc[o] = 0.f;

  const float* wbase = w1T + og * 32;   // [c][o], stride CMID; uniform
  for (int c = 0; c < CIN; ++c) {
    float lv = lo_l[c * WL + x];
    const float* wr = wbase + c * CMID;
#pragma unroll
    for (int o = 0; o < 32; ++o) acc[o] += wr[o] * lv;
  }
  const float* bb = b1 + og * 32;       // uniform
  float* tb = t + ((size_t)n * CMID + og * 32) * (HL * WL) + y * WL + x;
#pragma unroll
  for (int o = 0; o < 32; ++o) tb[(size_t)o * (HL * WL)] = acc[o] + bb[o];
}

// Fast erf (A&S 7.1.26, |err| <= 1.5e-7), DIV-FREE: v_rcp instead of IEEE divide.
__device__ __forceinline__ float erf_fast(float x) {
  float ax = fabsf(x);
  float t = __builtin_amdgcn_rcpf(fmaf(0.3275911f, ax, 1.f));
  float e = __expf(-ax * ax);
  float poly = t * (0.254829592f +
              t * (-0.284496736f +
              t * (1.421413741f +
              t * (-1.453152027f +
              t * 1.061405429f))));
  float r = fmaf(-poly, e, 1.f);
  return copysignf(r, x);
}

__device__ __forceinline__ float gelu_fast(float v) {
  float h = 0.5f * v;
  return fmaf(h, erf_fast(v * 0.70710678118654752f), h);
}

// K2 (templated on Q): per (n,c): partial sum & sumsq of GELU(upsample(t[n,c]))
// over output rows [Q*64, Q*64+64). Entire y-schedule compile-time; rolling
// register pair of x-interped rows. (unchanged from round 10)
template <int Q>
__global__ __launch_bounds__(256) void k2_statsT(const float* __restrict__ t,
                                                 float* __restrict__ S1p,
                                                 float* __restrict__ S2p) {
  constexpr int I0  = Q * 64;
  constexpr int YLO = (I0 * 127) / 255;
  constexpr int YHI0 = ((I0 + 63) * 127) / 255 + 1;
  constexpr int YHI = (YHI0 > 127) ? 127 : YHI0;
  constexpr int NR  = YHI - YLO + 1;            // 33 or 34
  int nc = blockIdx.x;                          // 2048 blocks
  __shared__ float img[NR * WL];
  __shared__ float red[16];
  int tid = threadIdx.x;
  const float* tb = t + (size_t)nc * (HL * WL) + YLO * WL;
  for (int f = tid; f < NR * (WL / 4); f += 256)
    ((float4*)img)[f] = ((const float4*)tb)[f];
  __syncthreads();

  float xs = tid * (127.f / 255.f);
  float x0f = floorf(xs);
  int x0 = (int)x0f, x1 = min(x0 + 1, 127);
  float wx = xs - x0f, omwx = 1.f - wx;

  auto xv = [&](int r) {
    return img[r * WL + x0] * omwx + img[r * WL + x1] * wx;
  };

  float sum = 0.f, ssq = 0.f;
  float cur0 = xv(0);                  // row y0(I0) == YLO
  float cur1 = xv(1);                  // NR >= 2 always
#pragma unroll
  for (int k = 0; k < 64; ++k) {
    const int i = I0 + k;
    const int y0k = (i * 127) / 255;                 // compile-time
    if (k > 0 && y0k != ((i - 1) * 127) / 255) {     // static advance
      cur0 = cur1;
      if (y0k + 1 <= YHI) cur1 = xv(y0k + 1 - YLO);
    }
    const float wyk = (float)(i * 127 - 255 * y0k) * (1.f / 255.f);  // exact
    float v = (y0k + 1 <= YHI) ? fmaf(cur0, 1.f - wyk, cur1 * wyk)
                               : cur0;               // i==255: wy==0
    float g = gelu_fast(v);
    sum += g; ssq += g * g;
  }
  int lane = tid & 63, w = tid >> 6;
#pragma unroll
  for (int d = 32; d; d >>= 1) {
    sum += __shfl_xor(sum, d, 64);
    ssq += __shfl_xor(ssq, d, 64);
  }
  if (lane == 0) { red[w] = sum; red[8 + w] = ssq; }
  __syncthreads();
  if (tid == 0) {
    S1p[Q * 2048 + nc] = red[0] + red[1] + red[2] + red[3];
    S2p[Q * 2048 + nc] = red[8] + red[9] + red[10] + red[11];
  }
}

// K2b: fold GN + SE + conv2 into per-image effective weights + bias.
// Weights are emitted as f16 MFMA A-fragments for v_mfma_f32_16x16x32_f16:
//   A[row=o&15][k=c&31] of tile (cb=c>>5, mt=o>>4); lane = ((c&31)>>3)*16 + (o&15),
//   element j = c&7  ->  wAf[((n*4+cb)*2+mt)*512 + lane*8 + j]
__global__ __launch_bounds__(128) void k2b_prep(const float* __restrict__ S1p,
                                                const float* __restrict__ S2p,
                                                const float* __restrict__ gn_w,
                                                const float* __restrict__ gn_b,
                                                const float* __restrict__ se_w1,
                                                const float* __restrict__ se_w2,
                                                const float* __restrict__ w2,
                                                unsigned short* __restrict__ wAf,
                                                float* __restrict__ beff) {
  int n = blockIdx.x, c = threadIdx.x;
  int nc = n * 128 + c;
  __shared__ float mArr[128], eArr[128], pArr[128], hArr[16], dArr[128];
  const float inv = 1.f / 65536.f;
  float m  = (S1p[nc] + S1p[2048 + nc] + S1p[4096 + nc] + S1p[6144 + nc]) * inv;
  float e2 = (S2p[nc] + S2p[2048 + nc] + S2p[4096 + nc] + S2p[6144 + nc]) * inv;
  mArr[c] = m; eArr[c] = e2;
  __syncthreads();
  int g0 = (c >> 6) << 6;
  float mu = 0.f, E2 = 0.f;
  for (int q = 0; q < 64; ++q) { mu += mArr[g0 + q]; E2 += eArr[g0 + q]; }
  mu *= (1.f / 64.f); E2 *= (1.f / 64.f);
  float var = E2 - mu * mu;
  float rs = rsqrtf(var + EPSV);
  float gw = gn_w[c], gb = gn_b[c];
  pArr[c] = (m - mu) * rs * gw + gb;
  __syncthreads();
  if (c < 16) {
    float h = 0.f;
    for (int q = 0; q < 128; ++q) h += se_w1[c * 128 + q] * pArr[q];
    hArr[c] = fmaxf(h, 0.f);
  }
  __syncthreads();
  float sacc = 0.f;
  for (int q = 0; q < 16; ++q) sacc += se_w2[c * 16 + q] * hArr[q];
  float s = __builtin_amdgcn_rcpf(1.f + __expf(-sacc));
  float a = s * gw * rs;
  float d = s * (gb - gw * rs * mu);
  dArr[c] = d;
  __syncthreads();
  int cb = c >> 5;
  int lbase = ((c >> 3) & 3) << 4;   // (lane>>4) = (c&31)>>3
  int j = c & 7;
#pragma unroll
  for (int o = 0; o < 32; ++o) {
    int mt = o >> 4;
    size_t idx = ((size_t)n * 8 + (size_t)(cb * 2 + mt)) * 512 +
                 (size_t)((lbase + (o & 15)) * 8 + j);
    _Float16 hv = (_Float16)(w2[o * 128 + c] * a);
    wAf[idx] = __builtin_bit_cast(unsigned short, hv);
  }
  if (c < 32) {
    float bb = 0.f;
    for (int q = 0; q < 128; ++q) bb += w2[c * 128 + q] * dArr[q];
    beff[n * 32 + c] = bb;
  }
}

// K3: MFMA conv2 + row softmax/cumsum epilogue. One 16.4 KB LDS region
// (ch/glb/D-phase share in place), XCD-chunked swizzle. Unchanged from round 10.
__global__ __launch_bounds__(256, 6) void k3_ref(const float* __restrict__ t,
                                                 const unsigned short* __restrict__ wAf,
                                                 const float* __restrict__ beff,
                                                 float* __restrict__ refodd,
                                                 float* __restrict__ gy) {
  int blk = (blockIdx.x & 7) * 512 + (blockIdx.x >> 3);  // bijective: 4096 = 8*512
  int n = blk >> 8, i = blk & 255;
  __shared__ float smem[4100];        // 16,400 B: 4096 shared ch/glb/D + 4 guard
  int tid = threadIdx.x;
  float* ch = smem;                   // f32 [32][128] view
  char* glb = (char*)smem;            // f16 B-panel view (256 rows x 64B), same bytes
  float* lmaxS = smem;                // epilogue alias (behind barrier)
  float* lsumS = smem + 64;
  const float* bn = beff + n * CO;    // uniform

  if (tid < 4) ch[4096 + tid] = 0.f;  // guard: finite for the x0+1 read at cc=31

  int lane = tid & 63;
  h8v wfrag[8];                       // A-frags: [cb][mt], resident all kernel
#pragma unroll
  for (int u = 0; u < 8; ++u)
    wfrag[u] = *(const h8v*)(wAf + ((size_t)n * 8 + u) * 512 + lane * 8);

  float ys = i * (127.f / 255.f);
  float y0f = floorf(ys);
  int y0 = (int)y0f, y1 = min(y0 + 1, 127);
  float wy = ys - y0f, omwy = 1.f - wy;
  float xs = tid * (127.f / 255.f);
  float x0f = floorf(xs);
  int x0 = (int)x0f;
  float wx = xs - x0f, omwx = 1.f - wx;

  f32x4 acc[2][4];
#pragma unroll
  for (int mt = 0; mt < 2; ++mt)
#pragma unroll
    for (int xt = 0; xt < 4; ++xt)
      acc[mt][xt] = (f32x4){0.f, 0.f, 0.f, 0.f};

  int wv6 = tid & 192;                // wave base pixel
  int cg = (tid >> 4) & 3;            // lane's k-granule within the B-frag
  const size_t tbase = (size_t)n * CMID * (HL * WL);

#pragma unroll
  for (int cb = 0; cb < 4; ++cb) {
    __syncthreads();                  // B0: prev mfma reads of glb done
    for (int f = tid; f < 32 * 32; f += 256) {
      int cc = f >> 5, x4 = (f & 31) * 4;
      const float* base = t + tbase + (size_t)(cb * 32 + cc) * (HL * WL) + x4;
      float4 a = *(const float4*)(base + y0 * WL);
      float4 b = *(const float4*)(base + y1 * WL);
      float4 cmb;
      cmb.x = fmaf(a.x, omwy, b.x * wy);
      cmb.y = fmaf(a.y, omwy, b.y * wy);
      cmb.z = fmaf(a.z, omwy, b.z * wy);
      cmb.w = fmaf(a.w, omwy, b.w * wy);
      *(float4*)&ch[cc * 128 + x4] = cmb;
    }
    __syncthreads();                  // B1: ch ready

    unsigned gp[16];
#pragma unroll
    for (int p = 0; p < 16; ++p) {
      const float* c0 = &ch[(2 * p) * 128 + x0];
      float g0 = gelu_fast(fmaf(c0[0], omwx, c0[1] * wx));
      const float* c1 = c0 + 128;
      float g1 = gelu_fast(fmaf(c1[0], omwx, c1[1] * wx));
      h2v hv;
      hv.x = (_Float16)g0;            // RNE casts for accuracy
      hv.y = (_Float16)g1;
      gp[p] = __builtin_bit_cast(unsigned, hv);
    }
    __syncthreads();                  // B2: ALL ch reads done; region reusable

    // write this pixel's 64B B-row IN PLACE, 16B chunks XOR-swizzled
    int xsw = (tid & 3) ^ ((tid >> 2) & 3);
    char* grow = glb + tid * 64;
    uint4 q;
    q.x = gp[0];  q.y = gp[1];  q.z = gp[2];  q.w = gp[3];
    *(uint4*)(grow + ((0 ^ xsw) << 4)) = q;
    q.x = gp[4];  q.y = gp[5];  q.z = gp[6];  q.w = gp[7];
    *(uint4*)(grow + ((1 ^ xsw) << 4)) = q;
    q.x = gp[8];  q.y = gp[9];  q.z = gp[10]; q.w = gp[11];
    *(uint4*)(grow + ((2 ^ xsw) << 4)) = q;
    q.x = gp[12]; q.y = gp[13]; q.z = gp[14]; q.w = gp[15];
    *(uint4*)(grow + ((3 ^ xsw) << 4)) = q;
    __syncthreads();                  // B3: glb ready

#pragma unroll
    for (int xt = 0; xt < 4; ++xt) {
      int xrow = wv6 + xt * 16 + (tid & 15);
      int slot = cg ^ (xrow & 3) ^ ((xrow >> 2) & 3);
      h8v bfrag = *(const h8v*)(glb + xrow * 64 + (slot << 4));
      acc[0][xt] = __builtin_amdgcn_mfma_f32_16x16x32_f16(wfrag[cb * 2 + 0], bfrag,
                                                          acc[0][xt], 0, 0, 0);
      acc[1][xt] = __builtin_amdgcn_mfma_f32_16x16x32_f16(wfrag[cb * 2 + 1], bfrag,
                                                          acc[1][xt], 0, 0, 0);
    }
  }

  // D-phase: intra-wave transpose through the same region, two half-phases of
  // 2 waves x 8KB slots (stride 128B, XOR-8 swizzle).
  float accv[32];
  int wv = tid >> 6;
#pragma unroll
  for (int phD = 0; phD < 2; ++phD) {
    __syncthreads();                  // region free (mfma/prev-phase reads done)
    if ((wv >> 1) == phD) {
      char* slotb = (char*)smem + (wv & 1) * 8192;
#pragma unroll
      for (int mt = 0; mt < 2; ++mt)
#pragma unroll
        for (int xt = 0; xt < 4; ++xt) {
          int lr = xt * 16 + (tid & 15);        // row within wave
          int go = mt * 4 + ((tid >> 4) & 3);   // o-chunk index (4 f32)
          *(f32x4*)(slotb + lr * 128 + ((go ^ (lr & 7)) << 4)) = acc[mt][xt];
        }
    }
    __syncthreads();                  // writes visible
    if ((wv >> 1) == phD) {
      char* slotb = (char*)smem + (wv & 1) * 8192;
      int lr = tid & 63;
#pragma unroll
      for (int gg = 0; gg < 8; ++gg) {
        f32x4 v = *(const f32x4*)(slotb + lr * 128 + ((gg ^ (lr & 7)) << 4));
        accv[4 * gg + 0] = v[0];
        accv[4 * gg + 1] = v[1];
        accv[4 * gg + 2] = v[2];
        accv[4 * gg + 3] = v[3];
      }
    }
  }
  __syncthreads();                    // all D reads done; lmaxS/lsumS may alias

#pragma unroll
  for (int o = 0; o < 32; ++o) accv[o] += bn[o];

  // odd channels -> refodd
#pragma unroll
  for (int k = 0; k < 16; ++k)
    refodd[(((size_t)(n * 16 + k)) * HO + i) * WO + tid] = accv[2 * k + 1];

  // even channels: row softmax + cumsum -> gy (batched phases).
  int lane2 = tid & 63, w = tid >> 6;
#pragma unroll
  for (int k = 0; k < 16; ++k) {
    float m = accv[2 * k];
#pragma unroll
    for (int d = 32; d; d >>= 1) m = fmaxf(m, __shfl_xor(m, d, 64));
    if (lane2 == 0) lmaxS[k * 4 + w] = m;
  }
  __syncthreads();
  float pk[16];
#pragma unroll
  for (int k = 0; k < 16; ++k) {
    float m = fmaxf(fmaxf(lmaxS[k * 4 + 0], lmaxS[k * 4 + 1]),
                    fmaxf(lmaxS[k * 4 + 2], lmaxS[k * 4 + 3]));
    float p = __expf(accv[2 * k] - m);
#pragma unroll
    for (int d = 1; d < 64; d <<= 1) {
      float q = __shfl_up(p, d, 64);
      if (lane2 >= d) p += q;
    }
    pk[k] = p;
    if (lane2 == 63) lsumS[k * 4 + w] = p;
  }
  __syncthreads();
#pragma unroll
  for (int k = 0; k < 16; ++k) {
    float off = 0.f, tot = 0.f;
#pragma unroll
    for (int q = 0; q < 4; ++q) {
      float x = lsumS[k * 4 + q];
      tot += x;
      if (q < w) off += x;
    }
    gy[((size_t)(n * 16 + k) * HO + i) * WO + tid] =
        (pk[k] + off) * (255.f * __builtin_amdgcn_rcpf(tot));
  }
}

// K5: column softmax+cumsum -> gx, in place over refodd.
__global__ __launch_bounds__(256) void k5_colscan(float* __restrict__ refodd) {
  int blk = blockIdx.x;           // nk*4 + cg
  int nk = blk >> 2, cg = blk & 3;
  int tid = threadIdx.x;
  int c = tid >> 6, j = tid & 63;
  __shared__ float lmax[4 * 64], lsum[4 * 64];
  float* img = refodd + (size_t)nk * (HO * WO) + cg * 64 + j;

  float p[64];
  float m = -1e30f;
#pragma unroll
  for (int q = 0; q < 64; ++q) {
    p[q] = img[(size_t)(c * 64 + q) * WO];
    m = fmaxf(m, p[q]);
  }
  lmax[c * 64 + j] = m;
  __syncthreads();
  m = fmaxf(fmaxf(lmax[j], lmax[64 + j]), fmaxf(lmax[128 + j], lmax[192 + j]));
  float s = 0.f;
#pragma unroll
  for (int q = 0; q < 64; ++q) {
    p[q] = __expf(p[q] - m);
    s += p[q];
  }
  lsum[c * 64 + j] = s;
  __syncthreads();
  float off = 0.f, tot = 0.f;
#pragma unroll
  for (int q2 = 0; q2 < 4; ++q2) {
    float x = lsum[q2 * 64 + j];
    tot += x;
    if (q2 < c) off += x;
  }
  float inv255 = 255.f * __builtin_amdgcn_rcpf(tot);
  float run = off;
#pragma unroll
  for (int q = 0; q < 64; ++q) {
    run += p[q];
    img[(size_t)(c * 64 + q) * WO] = run * inv255;
  }
}

// K6 v5: LANE = COLUMN remap. The flow is ~identity (gx~j, gy~i), so with the
// old lane=row mapping each tap was a 64-distinct-line gather (TA-serialized,
// ~64 TA-cycles per vector load -- the real k6 bottleneck). Now thread
// (jl=tid&63, ig=tid>>6) owns a 16-row x 1-col slice: for each tap s the
// wave's 64 lanes read hi at consecutive columns of ~the same row -> 1-3
// lines per load. Coord reads / result writes are stride-65 LDS at
// lane-stride-1 (conflict-free). Staging, deep-MLP barrier, and dense-store
// phases unchanged. gy aliases out: all reads precede the barrier.
__global__ __launch_bounds__(256, 4) void k6_sample_t5(const float* __restrict__ gx,
                                                       const float* __restrict__ hi,
                                                       float* out) {
  int blk = (blockIdx.x & 7) * 512 + (blockIdx.x >> 3);  // bijective: 4096 = 8*512
  int nk = blk >> 4, ti = (blk >> 2) & 3, tj = blk & 3;
  __shared__ float gxl[64 * 65];   // coords; becomes result tile
  __shared__ float gyl[64 * 65];
  int tid = threadIdx.x;
  const size_t ibase = (size_t)nk * (HO * WO);
  const size_t tb = ibase + (size_t)(ti * 64) * WO + tj * 64;
  const float* himg = hi + ibase;

  // Phase 0: dense coalesced stage of gx and gy (gy aliases out).
#pragma unroll
  for (int ph = 0; ph < 4; ++ph) {
    int r = ph * 16 + (tid >> 4), c4 = (tid & 15) * 4;
    float4 vx = *(const float4*)(gx + tb + (size_t)r * WO + c4);
    float4 vy = *(const float4*)(out + tb + (size_t)r * WO + c4);
    int a = r * 65 + c4;
    gxl[a] = vx.x; gxl[a + 1] = vx.y; gxl[a + 2] = vx.z; gxl[a + 3] = vx.w;
    gyl[a] = vy.x; gyl[a + 1] = vy.y; gyl[a + 2] = vy.z; gyl[a + 3] = vy.w;
  }
  __syncthreads();

  // Phase 1: thread (col jl, rows ig*16..+15) reads its 32 coords from LDS
  // (lane-stride 1 within each row -> conflict-free) and issues ALL 64 taps.
  // Coords in (0,255]: x0,y0 in-bounds; clamped +1 taps carry ~0 weight
  // (zero-padding semantics). Branchless.
  int jl = tid & 63, ig = tid >> 6;
  const float* lgx = &gxl[jl];
  const float* lgy = &gyl[jl];
  float wxa[16], wya[16];
  float v00[16], v01[16], v10[16], v11[16];
#pragma unroll
  for (int s = 0; s < 16; ++s) {
    int r = ig * 16 + s;
    float xf = lgx[r * 65], yf = lgy[r * 65];
    float x0f = floorf(xf), y0f = floorf(yf);
    wxa[s] = xf - x0f; wya[s] = yf - y0f;
    int x0 = (int)x0f, y0 = (int)y0f;
    int x1 = min(x0 + 1, 255), y1 = min(y0 + 1, 255);
    const float* r0 = himg + y0 * WO;
    const float* r1 = himg + y1 * WO;
    v00[s] = r0[x0]; v01[s] = r0[x1];
    v10[s] = r1[x0]; v11[s] = r1[x1];
  }
  // Real compiler memory barrier: loads cannot sink past it.
  asm volatile("" ::: "memory");
  __syncthreads();

  // Phase 2: bilinear combine; results overwrite gxl (same slots just read).
  float* lres = &gxl[jl];
#pragma unroll
  for (int s = 0; s < 16; ++s) {
    int r = ig * 16 + s;
    float top = fmaf(v01[s] - v00[s], wxa[s], v00[s]);
    float bot = fmaf(v11[s] - v10[s], wxa[s], v10[s]);
    lres[r * 65] = fmaf(bot - top, wya[s], top);
  }
  __syncthreads();

  // Phase 3: dense store (wave covers 16 full 256B rows).
#pragma unroll
  for (int ph = 0; ph < 4; ++ph) {
    int r = ph * 16 + (tid >> 4), c4 = (tid & 15) * 4;
    int a = r * 65 + c4;
    float4 v;
    v.x = gxl[a]; v.y = gxl[a + 1]; v.z = gxl[a + 2]; v.w = gxl[a + 3];
    *(float4*)(out + tb + (size_t)r * WO + c4) = v;
  }
}

extern "C" void kernel_launch(void* const* d_in, const int* in_sizes, int n_in,
                              void* d_out, int out_size, void* d_ws, size_t ws_size,
                              hipStream_t stream) {
  (void)in_sizes; (void)n_in; (void)out_size; (void)ws_size;
  const float* lo  = (const float*)d_in[0];
  const float* hi  = (const float*)d_in[1];
  const float* w1  = (const float*)d_in[2];
  const float* b1  = (const float*)d_in[3];
  const float* gnw = (const float*)d_in[4];
  const float* gnb = (const float*)d_in[5];
  const float* sw1 = (const float*)d_in[6];
  const float* sw2 = (const float*)d_in[7];
  const float* w2  = (const float*)d_in[8];
  float* ws = (float*)d_ws;
  float* t       = ws;                    // 33,554,432 floats
  float* refodd  = ws + 33554432;         // 16,777,216 floats (becomes gx in place)
  float* S1p     = ws + 50331648;         // 8192
  float* S2p     = S1p + 8192;            // 8192
  unsigned short* wAf = (unsigned short*)(S2p + 8192);  // 65,536 f16 in old w2effT slot
  float* beff    = S2p + 8192 + 65536;    // 512
  float* w1T     = beff + 512;            // 8192
  float* out     = (float*)d_out;
  float* gybuf   = out;                   // gy aliases d_out

  k0_transpose<<<dim3(1), dim3(256), 0, stream>>>(w1, w1T);
  k1_conv1<<<dim3(2048), dim3(512), 0, stream>>>(lo, w1T, b1, t);
  k2_statsT<0><<<dim3(2048), dim3(256), 0, stream>>>(t, S1p, S2p);
  k2_statsT<1><<<dim3(2048), dim3(256), 0, stream>>>(t, S1p, S2p);
  k2_statsT<2><<<dim3(2048), dim3(256), 0, stream>>>(t, S1p, S2p);
  k2_statsT<3><<<dim3(2048), dim3(256), 0, stream>>>(t, S1p, S2p);
  k2b_prep<<<dim3(16), dim3(128), 0, stream>>>(S1p, S2p, gnw, gnb, sw1, sw2, w2, wAf, beff);
  k3_ref<<<dim3(4096), dim3(256), 0, stream>>>(t, wAf, beff, refodd, gybuf);
  k5_colscan<<<dim3(1024), dim3(256), 0, stream>>>(refodd);
  k6_sample_t5<<<dim3(4096), dim3(256), 0, stream>>>(refodd, hi, out);
}